// Round 8
// baseline (398.202 us; speedup 1.0000x reference)
//
#include <hip/hip_runtime.h>
#include <hip/hip_bf16.h>
#include <cstddef>

#define NPIX 262144   // 512*512
#define PW 514        // padded width/height
typedef __hip_bfloat16 bf16;
typedef __attribute__((ext_vector_type(8))) short short8;
typedef __attribute__((ext_vector_type(4))) float f32x4;

__device__ inline unsigned short f2bfu(float f){
  __hip_bfloat16 h = __float2bfloat16(f);
  return *(reinterpret_cast<unsigned short*>(&h));
}
__device__ inline float bflo(unsigned u){ return __uint_as_float(u<<16); }
__device__ inline float bfhi(unsigned u){ return __uint_as_float(u & 0xffff0000u); }
// cheap pair pack: round-half-up bf16, low16=a, high16=b (values finite here)
__device__ inline unsigned pack2bf(float a, float b){
  unsigned ua = __float_as_uint(a), ub = __float_as_uint(b);
  return ((ua + 0x8000u) >> 16) | ((ub + 0x8000u) & 0xffff0000u);
}
// async global->LDS 16B DMA (wave-uniform LDS base + lane*16; gptr per-lane)
// HAZARD NOTE (r5/r6 post-mortem): keep the outstanding LDS-DMA queue SHALLOW (<= ~3-6
// instructions/wave, drained by the next __syncthreads within ~1 compute phase). Full
// prefetch of 9 DMAs/wave across a single barrier produced sporadic LDS corruption
// (absmax 0.0078 -> 128) on gfx950 even with a full vmcnt(0) drain. Mechanism unproven;
// do not deepen the queue without a race screen.
__device__ inline void dma16(const bf16* g, unsigned short* l){
  __builtin_amdgcn_global_load_lds(
      (const __attribute__((address_space(1))) unsigned int*)g,
      (__attribute__((address_space(3))) unsigned int*)l, 16, 0, 0);
}

// group-norm affine from accumulated stats (8 channels per group, 262144 px)
__device__ inline void computeAB(const float* stats, const float* gamma, const float* beta,
                                 int c, float& A, float& B){
  int g = c >> 3;
  const float invN = 1.f/2097152.f;
  float m = stats[g*2]*invN;
  float v = stats[g*2+1]*invN - m*m;
  float inv = rsqrtf(v + 1e-5f);
  A = inv*gamma[c];
  B = beta[c] - m*A;
}

// GN+ReLU on 8 bf16 channels packed in a uint4; pure SSA; border -> 0 via SELECT (NaN-safe).
// Numerics verified r3/r4 (absmax 0.0078125) -- identical chain to the old norm_kernel.
__device__ inline uint4 gnrelu16(uint4 v, const float* __restrict__ ab, bool border){
  unsigned uu[4] = {v.x, v.y, v.z, v.w};
  unsigned ou[4];
  #pragma unroll
  for (int j = 0; j < 4; ++j){
    f32x4 abv = *(const f32x4*)(ab + j*4);    // A(2j),B(2j),A(2j+1),B(2j+1)
    float a = fmaxf(bflo(uu[j])*abv[0] + abv[1], 0.f);
    float d = fmaxf(bfhi(uu[j])*abv[2] + abv[3], 0.f);
    ou[j] = pack2bf(a, d);
  }
  if (border) return make_uint4(0u,0u,0u,0u);
  return make_uint4(ou[0], ou[1], ou[2], ou[3]);
}

// ---------------- merged setup: zero init + all 5 weight transforms ----------------
__global__ void setup_kernel(float* out, float* stats, float* pooled,
                             const float* __restrict__ w1, bf16* __restrict__ wT1,
                             const float* __restrict__ w2, bf16* __restrict__ wT2,
                             const float* __restrict__ w3, bf16* __restrict__ wT3,
                             const float* __restrict__ fw1, bf16* __restrict__ wF1T,
                             const float* __restrict__ fw2, bf16* __restrict__ wF2T){
  int b = blockIdx.x;
  if (b < 1025){
    int i = b*256 + threadIdx.x;
    if (i < 262147) out[i] = 0.f;            // grid + log_prob + entropy + value
    if (i < 68)  stats[i]  = 0.f;
    if (i < 128) pooled[i] = 0.f;
    return;
  }
  b -= 1025;
  if (b < 30){   // conv1 weights: [kc5][oc48][kp32], k = tap*16 + c
    int idx = b*256 + threadIdx.x;
    if (idx < 5*48*32){
      int kp = idx & 31; int oc = (idx >> 5) % 48; int kc = idx / (48*32);
      int k = kc*32 + kp;
      int tap = k >> 4, c = k & 15;
      float v = (tap < 9 && c < 14) ? w1[(oc*14 + c)*9 + tap] : 0.f;
      wT1[idx] = __float2bfloat16(v);
    }
    return;
  }
  b -= 30;
  if (b < 216){  // conv2 weights: [tap][cc2][oc96][cp32] (ic 48..63 zero!)
    int idx = b*256 + threadIdx.x;
    if (idx < 9*2*96*32){
      int cp = idx & 31; int rest = idx >> 5;
      int oc = rest % 96; rest /= 96;
      int cc = rest % 2; int tap = rest / 2;
      int ic = cc*32 + cp;
      float v = (ic < 48) ? w2[(oc*48 + ic)*9 + tap] : 0.f;
      wT2[idx] = __float2bfloat16(v);
    }
    return;
  }
  b -= 216;
  if (b < 432){  // conv3 weights: [tap][cc3][oc128][cp32]
    int idx = b*256 + threadIdx.x;
    if (idx < 9*3*128*32){
      int cp = idx & 31; int rest = idx >> 5;
      int oc = rest & 127; rest >>= 7;
      int cc = rest % 3; int tap = rest / 3;
      int ic = cc*32 + cp;
      float v = (ic < 96) ? w3[(oc*96 + ic)*9 + tap] : 0.f;
      wT3[idx] = __float2bfloat16(v);
    }
    return;
  }
  b -= 432;
  if (b < 1152){ // fc1 weights: [kc36][oc256][kp32], k' = rr*128 + ch (tap-major)
    int idx = b*256 + threadIdx.x;
    if (idx < 36*256*32){
      int kp = idx & 31; int oc = (idx >> 5) & 255; int kc = idx >> 13;
      int k2 = kc*32 + kp;
      int rr = k2 >> 7, ch = k2 & 127;
      wF1T[idx] = __float2bfloat16(fw1[(size_t)(ch*9 + rr)*256 + oc]);
    }
    return;
  }
  b -= 1152;
  {              // fc2 weights: [kc8][oc128][kp32]
    int idx = b*256 + threadIdx.x;
    if (idx < 8*128*32){
      int kp = idx & 31; int oc = (idx >> 5) & 127; int kc = idx >> 12;
      wF2T[idx] = __float2bfloat16(fw2[(size_t)(kc*32 + kp)*128 + oc]);
    }
  }
}

// ---------------- conv1 MFMA: 14ch fp32 NCHW -> 48ch raw bf16 padded NHWC, + stats ----------------
__launch_bounds__(256,2)
__global__ void conv1_mfma_kernel(const float* __restrict__ x, const bf16* __restrict__ wT,
                                  const float* __restrict__ bias, bf16* __restrict__ out,
                                  float* __restrict__ stats){
  constexpr int XP = 24;
  __shared__ unsigned short sX[324*XP];
  __shared__ float sStat[96];
  const int tid = threadIdx.x;
  const int lane = tid & 63, wave = tid >> 6;
  const int quad = lane >> 4, l15 = lane & 15;
  const int tileX = (blockIdx.x & 31)*16, tileY = (blockIdx.x >> 5)*16;
  if (tid < 96) sStat[tid] = 0.f;
  for (int p = tid; p < 324; p += 256){ sX[p*XP+14] = 0; sX[p*XP+15] = 0; }
  for (int idx = tid; idx < 14*324; idx += 256){
    int c = idx / 324, p = idx - c*324;
    int r = p / 18, col = p - r*18;
    int gy = tileY + r - 1, gx = tileX + col - 1;
    float v = 0.f;
    if ((unsigned)gy < 512u && (unsigned)gx < 512u) v = x[(size_t)c*NPIX + gy*512 + gx];
    sX[p*XP + c] = f2bfu(v);
  }
  __syncthreads();

  f32x4 acc[3][4];
  #pragma unroll
  for (int t = 0; t < 3; ++t){
    f32x4 bv = *(const f32x4*)(bias + t*16 + quad*4);
    #pragma unroll
    for (int s = 0; s < 4; ++s) acc[t][s] = bv;
  }
  const int pxb = wave*4;
  const int h = quad >> 1, chalf = (quad & 1)*8;
  const int T0[5] = {0,2,4,6,8};
  const int T1[5] = {1,3,5,7,8};
  #pragma unroll
  for (int kc = 0; kc < 5; ++kc){
    short8 a[3];
    #pragma unroll
    for (int t = 0; t < 3; ++t)
      a[t] = *(const short8*)((const unsigned short*)wT + (size_t)(kc*48 + t*16 + l15)*32 + quad*8);
    const int ky = h ? (T1[kc]/3) : (T0[kc]/3);
    const int kx = h ? (T1[kc]%3) : (T0[kc]%3);
    #pragma unroll
    for (int s = 0; s < 4; ++s){
      int py = pxb + s;
      short8 bfr = *(const short8*)(&sX[((py+ky)*18 + l15+kx)*XP + chalf]);
      #pragma unroll
      for (int t = 0; t < 3; ++t)
        acc[t][s] = __builtin_amdgcn_mfma_f32_16x16x32_bf16(a[t], bfr, acc[t][s], 0, 0, 0);
    }
  }
  #pragma unroll
  for (int t = 0; t < 3; ++t){
    #pragma unroll
    for (int r = 0; r < 4; ++r){
      float sv = 0.f, sq = 0.f;
      #pragma unroll
      for (int s = 0; s < 4; ++s){ float v = acc[t][s][r]; sv += v; sq += v*v; }
      #pragma unroll
      for (int m = 1; m < 16; m <<= 1){ sv += __shfl_xor(sv, m); sq += __shfl_xor(sq, m); }
      if (l15 == 0){
        atomicAdd(&sStat[(t*16 + quad*4 + r)*2],   sv);
        atomicAdd(&sStat[(t*16 + quad*4 + r)*2+1], sq);
      }
    }
    #pragma unroll
    for (int s = 0; s < 4; ++s){
      f32x4 v = acc[t][s];
      uint2 pk;
      pk.x = pack2bf(v[0], v[1]);
      pk.y = pack2bf(v[2], v[3]);
      *(uint2*)(out + ((size_t)(tileY+pxb+s+1)*PW + tileX+l15+1)*48 + t*16 + quad*4) = pk;
    }
  }
  __syncthreads();
  if (tid < 12){
    int g = tid >> 1, wsel = tid & 1;
    float v = 0.f;
    #pragma unroll
    for (int j = 0; j < 8; ++j) v += sStat[(g*8+j)*2 + wsel];
    atomicAdd(&stats[g*2 + wsel], v);
  }
}

// ---------------- conv2: 16x16-tile MFMA conv + FUSED input GN (in-LDS transform) ----------------
// r7-verified DMA/compute structure; after each chunk's DMA-drain barrier, each thread
// normalizes its OWN staged slots in LDS (ds_read_b128 -> gnrelu16 -> ds_write_b128), next
// barrier publishes. Replaces the 51 MB norm48 global RMW pass. Border slots -> 0 via select.
template<int IC, int NCC, int OCT, int OC>
__launch_bounds__(256, 2)
__global__ void conv_dma16_kernel(const bf16* __restrict__ in, const bf16* __restrict__ wT,
                                  const float* __restrict__ bias,
                                  const float* __restrict__ instats,
                                  const float* __restrict__ gamma, const float* __restrict__ beta,
                                  bf16* __restrict__ out, float* __restrict__ outstats){
  constexpr int CPAD = NCC*32;                  // padded channel count (A=B=0 beyond IC)
  __shared__ unsigned short sIn[2][1296*8];     // 2 x 20736 B
  __shared__ float sStat[2*OC];
  __shared__ __align__(16) float sAB2[2*CPAD];  // interleaved {A,B} per channel
  const int tid  = threadIdx.x;
  const int lane = tid & 63, wave = tid >> 6;
  const int quad = lane >> 4, l15 = lane & 15;
  const int ocg = wave >> 1, pxg = wave & 1;
  const int tileX = (blockIdx.x & 31) * 16, tileY = (blockIdx.x >> 5) * 16;
  const int ocbase = ocg * (OCT*16);

  for (int i = tid; i < 2*OC; i += 256) sStat[i] = 0.f;
  for (int c = tid; c < CPAD; c += 256){
    float A = 0.f, B = 0.f;
    if (c < IC) computeAB(instats, gamma, beta, c, A, B);
    sAB2[2*c] = A; sAB2[2*c+1] = B;
  }

  // per-thread slot metadata, computed ONCE (chunk adds cr*32 channels / cr*64 AB floats)
  unsigned off[6]; int cbk[6]; bool bfk[6];
  #pragma unroll
  for (int k = 0; k < 6; ++k){
    int slot = tid + k*256;
    if (k < 5 || tid < 16){
      int row = slot/72; int rem = slot - row*72;
      int cc = rem/18;   int col = rem - cc*18;
      int py = tileY + row, px = tileX + col;
      // for IC=48, chunk 1 cc>=2 reads past-channel raw data; A=B=0 zeroes it (NaN-safe).
      off[k] = (unsigned)((py*PW + px)*IC + cc*8);
      cbk[k] = cc*16;
      bfk[k] = (py==0) | (py==513) | (px==0) | (px==513);
    }
  }
  auto issueDMA = [&](int cr, int bi){
    #pragma unroll
    for (int k = 0; k < 6; ++k){
      if (k == 5 && tid >= 16) continue;
      dma16(in + off[k] + cr*32, &sIn[bi][(tid + k*256)*8]);
    }
  };
  auto transformLDS = [&](int cr, int bi){
    #pragma unroll
    for (int k = 0; k < 6; ++k){
      if (k == 5 && tid >= 16) continue;
      uint4* p = (uint4*)&sIn[bi][(tid + k*256)*8];
      *p = gnrelu16(*p, &sAB2[cbk[k] + cr*64], bfk[k]);
    }
  };

  f32x4 acc[OCT][8];
  #pragma unroll
  for (int t = 0; t < OCT; ++t){
    f32x4 bv = *(const f32x4*)(bias + ocbase + t*16 + quad*4);
    #pragma unroll
    for (int s = 0; s < 8; ++s) acc[t][s] = bv;
  }

  auto computeChunk = [&](int cr, int bi){
    const unsigned short* B0 = &sIn[bi][(((pxg*8)*4 + quad)*18 + l15)*8];
    const unsigned short* W0 = (const unsigned short*)wT + ((size_t)cr*OC + ocbase + l15)*32 + quad*8;
    #pragma unroll
    for (int tap = 0; tap < 9; ++tap){
      const int ky = tap/3, kx = tap - ky*3;
      short8 a[OCT];
      #pragma unroll
      for (int t = 0; t < OCT; ++t)
        a[t] = *(const short8*)(W0 + (size_t)tap*(NCC*OC*32) + t*512);
      #pragma unroll
      for (int s = 0; s < 8; ++s){
        short8 b = *(const short8*)(B0 + ((s+ky)*72 + kx)*8);
        #pragma unroll
        for (int t = 0; t < OCT; ++t)
          acc[t][s] = __builtin_amdgcn_mfma_f32_16x16x32_bf16(a[t], b, acc[t][s], 0, 0, 0);
      }
    }
  };

  // ---- schedule (NCC=2): 3 barriers, DMA queue <=6 outstanding at any drain ----
  issueDMA(0, 0);
  __syncthreads();               // chunk0 raw visible; sStat/sAB2 ready
  issueDMA(1, 1);
  transformLDS(0, 0);            // normalize buf0 in place
  __syncthreads();               // buf0 normalized visible; chunk1 raw drained+visible
  transformLDS(1, 1);            // VALU/LDS interleaves ahead of MFMA below
  computeChunk(0, 0);
  __syncthreads();               // buf1 normalized visible
  computeChunk(1, 1);

  // stats + store raw bf16
  #pragma unroll
  for (int t = 0; t < OCT; ++t){
    #pragma unroll
    for (int r = 0; r < 4; ++r){
      float sv = 0.f, sq = 0.f;
      #pragma unroll
      for (int s = 0; s < 8; ++s){ float v = acc[t][s][r]; sv += v; sq += v*v; }
      #pragma unroll
      for (int m = 1; m < 16; m <<= 1){ sv += __shfl_xor(sv, m); sq += __shfl_xor(sq, m); }
      if (l15 == 0){
        atomicAdd(&sStat[(ocbase + t*16 + quad*4 + r)*2],   sv);
        atomicAdd(&sStat[(ocbase + t*16 + quad*4 + r)*2+1], sq);
      }
    }
    #pragma unroll
    for (int s = 0; s < 8; ++s){
      int py = pxg*8 + s;
      f32x4 v = acc[t][s];
      uint2 pk;
      pk.x = pack2bf(v[0], v[1]);
      pk.y = pack2bf(v[2], v[3]);
      *(uint2*)(out + ((size_t)(tileY+py+1)*PW + (tileX+l15+1))*OC + ocbase + t*16 + quad*4) = pk;
    }
  }
  __syncthreads();
  if (tid < (OC/8)*2){
    int g = tid >> 1, wsel = tid & 1;
    float v = 0.f;
    #pragma unroll
    for (int j = 0; j < 8; ++j) v += sStat[(g*8+j)*2 + wsel];
    atomicAdd(&outstats[g*2 + wsel], v);
  }
}

// ---------------- conv3: 16x8-tile MFMA conv, r-major taps + FUSED input GN (in-LDS) ----------------
// r7-verified structure + tri-buffer LDS (one buffer per chunk, never reused -> no WAR) with
// FULL __syncthreads between phases and shallow DMA queues (<=K=3 outstanding at any drain;
// r5/r6 hazard respected). DMA(2) issued right after barrier 2 -> full compute(0) of cover.
// Replaces the 101 MB norm96 global RMW pass.
template<int IC, int NCC, int OCT, int OC, int NW, int TH>
__launch_bounds__(NW*64, 3)
__global__ void conv_dma8_kernel(const bf16* __restrict__ in, const bf16* __restrict__ wT,
                                 const float* __restrict__ bias,
                                 const float* __restrict__ instats,
                                 const float* __restrict__ gamma, const float* __restrict__ beta,
                                 bf16* __restrict__ out, float* __restrict__ outstats){
  constexpr int NT   = NW*64;
  constexpr int ROWS = TH + 2;
  constexpr int SLOTS = ROWS * 72;              // 16B slots per chunk
  constexpr int K    = (SLOTS + NT - 1) / NT;
  constexpr int REM  = SLOTS - (K-1)*NT;        // active threads in last k
  constexpr int CPAD = NCC*32;
  static_assert(NCC == 3, "conv3 path");
  __shared__ unsigned short sIn[NCC][SLOTS*8];  // 3 x 11520 B, one buffer per chunk
  __shared__ float sStat[2*OC];
  __shared__ __align__(16) float sAB2[2*CPAD];
  const int tid  = threadIdx.x;
  const int lane = tid & 63, wave = tid >> 6;
  const int quad = lane >> 4, l15 = lane & 15;
  const int tileX = (blockIdx.x & 31) * 16, tileY = (blockIdx.x >> 5) * TH;
  const int ocbase = wave * (OCT*16);

  for (int i = tid; i < 2*OC; i += NT) sStat[i] = 0.f;
  for (int c = tid; c < CPAD; c += NT){
    float A = 0.f, B = 0.f;
    if (c < IC) computeAB(instats, gamma, beta, c, A, B);
    sAB2[2*c] = A; sAB2[2*c+1] = B;
  }

  // per-thread slot metadata, computed ONCE (chunk adds cr*32 channels / cr*64 AB floats)
  unsigned off[K]; int cbk[K]; bool bfk[K];
  #pragma unroll
  for (int k = 0; k < K; ++k){
    int slot = tid + k*NT;
    if (k < K-1 || tid < REM){
      int row = slot/72; int rem = slot - row*72;
      int cc = rem/18;   int col = rem - cc*18;
      int py = tileY + row, px = tileX + col;
      off[k] = (unsigned)((py*PW + px)*IC + cc*8);
      cbk[k] = cc*16;
      bfk[k] = (py==0) | (py==513) | (px==0) | (px==513);
    }
  }
  auto issueDMA = [&](int cr){
    #pragma unroll
    for (int k = 0; k < K; ++k){
      if (k == K-1 && tid >= REM) continue;
      dma16(in + off[k] + cr*32, &sIn[cr][(tid + k*NT)*8]);
    }
  };
  auto transformLDS = [&](int cr){
    #pragma unroll
    for (int k = 0; k < K; ++k){
      if (k == K-1 && tid >= REM) continue;
      uint4* p = (uint4*)&sIn[cr][(tid + k*NT)*8];
      *p = gnrelu16(*p, &sAB2[cbk[k] + cr*64], bfk[k]);
    }
  };

  f32x4 acc[OCT][TH];
  #pragma unroll
  for (int t = 0; t < OCT; ++t){
    f32x4 bv = *(const f32x4*)(bias + ocbase + t*16 + quad*4);
    #pragma unroll
    for (int s = 0; s < TH; ++s) acc[t][s] = bv;
  }

  auto computeChunk = [&](int cr){
    // wave-shared b base: all row/kx offsets are compile-time immediates from here
    const unsigned short* B0 = &sIn[cr][(quad*18 + l15)*8];
    const unsigned short* W0 = (const unsigned short*)wT + ((size_t)cr*OC + ocbase + l15)*32 + quad*8;
    #pragma unroll
    for (int kx = 0; kx < 3; ++kx){
      short8 a[3][OCT];
      #pragma unroll
      for (int ky = 0; ky < 3; ++ky)
        #pragma unroll
        for (int t = 0; t < OCT; ++t)
          a[ky][t] = *(const short8*)(W0 + (size_t)(ky*3+kx)*(NCC*OC*32) + t*512);
      #pragma unroll
      for (int r = 0; r < ROWS; ++r){
        short8 b = *(const short8*)(B0 + (r*72 + kx)*8);
        #pragma unroll
        for (int ky = 0; ky < 3; ++ky){
          const int s = r - ky;
          if (s >= 0 && s < TH){
            #pragma unroll
            for (int t = 0; t < OCT; ++t)
              acc[t][s] = __builtin_amdgcn_mfma_f32_16x16x32_bf16(a[ky][t], b, acc[t][s], 0, 0, 0);
          }
        }
      }
    }
  };

  // ---- schedule (NCC=3): 4 barriers, DMA queue <=K outstanding at any drain ----
  issueDMA(0);
  __syncthreads();               // chunk0 raw visible; sStat/sAB2 ready
  issueDMA(1);
  transformLDS(0);
  __syncthreads();               // buf0 normalized visible; chunk1 raw drained+visible
  issueDMA(2);                   // full compute(0) of latency cover
  transformLDS(1);
  computeChunk(0);
  __syncthreads();               // buf1 normalized visible; chunk2 raw drained+visible
  transformLDS(2);
  computeChunk(1);
  __syncthreads();               // buf2 normalized visible
  computeChunk(2);

  // stats + store raw bf16
  #pragma unroll
  for (int t = 0; t < OCT; ++t){
    #pragma unroll
    for (int r = 0; r < 4; ++r){
      float sv = 0.f, sq = 0.f;
      #pragma unroll
      for (int s = 0; s < TH; ++s){ float v = acc[t][s][r]; sv += v; sq += v*v; }
      #pragma unroll
      for (int m = 1; m < 16; m <<= 1){ sv += __shfl_xor(sv, m); sq += __shfl_xor(sq, m); }
      if (l15 == 0){
        atomicAdd(&sStat[(ocbase + t*16 + quad*4 + r)*2],   sv);
        atomicAdd(&sStat[(ocbase + t*16 + quad*4 + r)*2+1], sq);
      }
    }
    #pragma unroll
    for (int s = 0; s < TH; ++s){
      f32x4 v = acc[t][s];
      uint2 pk;
      pk.x = pack2bf(v[0], v[1]);
      pk.y = pack2bf(v[2], v[3]);
      *(uint2*)(out + ((size_t)(tileY+s+1)*PW + (tileX+l15+1))*OC + ocbase + t*16 + quad*4) = pk;
    }
  }
  __syncthreads();
  if (tid < (OC/8)*2){
    int g = tid >> 1, wsel = tid & 1;
    float v = 0.f;
    #pragma unroll
    for (int j = 0; j < 8; ++j) v += sStat[(g*8+j)*2 + wsel];
    atomicAdd(&outstats[g*2 + wsel], v);
  }
}

// ---------------- MEGA: gather+GN+ReLU -> FC1(MFMA) -> FC2(MFMA) -> heads ->
//                  log_prob/entropy/scatter, plus 1 pool row per block. 512 blocks x 16 cells. ----
__launch_bounds__(256)
__global__ void mega_kernel(const bf16* __restrict__ f, const float* __restrict__ instats,
                            const float* __restrict__ gamma, const float* __restrict__ beta,
                            const int* __restrict__ cell_i, const int* __restrict__ cell_j,
                            const int* __restrict__ action,
                            const bf16* __restrict__ wT, const float* __restrict__ fb1,
                            const bf16* __restrict__ wT2, const float* __restrict__ fb2,
                            const float* __restrict__ bw, const float* __restrict__ bb,
                            const float* __restrict__ iw, const float* __restrict__ ib,
                            const float* __restrict__ tw, const float* __restrict__ tb,
                            float* __restrict__ pooled, float* __restrict__ out){
  constexpr int KST = 1160;               // fc1 k stride (shorts)
  __shared__ unsigned short sG[16*KST];   // 37120 B; overlaid by h2L after FC1 reads done
  __shared__ unsigned short h1L[16*264];  // 8448 B
  __shared__ float sAB[256];
  __shared__ int sij[32];
  __shared__ float sRed[2];
  __shared__ float sP[128];
  float* h2L = (float*)sG;                // 16*132 fp32 = 8448 B (inside sG)
  const int tid = threadIdx.x;
  const int lane = tid & 63, wave = tid >> 6;
  const int quad = lane >> 4, l15 = lane & 15;
  const int cb = blockIdx.x*16;

  if (tid < 2) sRed[tid] = 0.f;
  if (tid < 128){ float A,B; computeAB(instats, gamma, beta, tid, A, B);
    sAB[tid]=A; sAB[128+tid]=B; sP[tid]=0.f; }
  if (tid < 16) sij[tid] = cell_i[cb + tid];
  else if (tid < 32) sij[tid] = cell_j[cb + tid - 16];
  __syncthreads();

  // phase 1: gather 16 cells' 3x3x128 patches (GN+ReLU) -> sG [cell][k'=rr*128+ch]
  for (int idx = tid; idx < 16*144; idx += 256){
    int c8 = idx & 15; int t2 = idx >> 4;
    int cell = t2 / 9, rr = t2 - cell*9;
    int r = rr/3, cl = rr - r*3;
    int py = sij[cell] + r, px = sij[16+cell] + cl;   // padded coords
    uint4 v = *(const uint4*)(f + ((size_t)py*PW + px)*128 + c8*8);
    bool border = (py==0) | (py==513) | (px==0) | (px==513);
    unsigned uu[4] = {v.x, v.y, v.z, v.w};
    unsigned ou[4];
    #pragma unroll
    for (int j = 0; j < 4; ++j){
      int ch = c8*8 + j*2;
      float a = border ? 0.f : fmaxf(bflo(uu[j])*sAB[ch]   + sAB[128+ch],   0.f);
      float d = border ? 0.f : fmaxf(bfhi(uu[j])*sAB[ch+1] + sAB[128+ch+1], 0.f);
      ou[j] = pack2bf(a, d);
    }
    uint4 wv; wv.x = ou[0]; wv.y = ou[1]; wv.z = ou[2]; wv.w = ou[3];
    *(uint4*)(&sG[cell*KST + rr*128 + c8*8]) = wv;
  }
  __syncthreads();

  // phase 2: FC1 MFMA (1152 -> 256), wave owns oc [wave*64, wave*64+64)
  {
    f32x4 acc[4];
    const int ocb = wave*64;
    #pragma unroll
    for (int t = 0; t < 4; ++t)
      acc[t] = *(const f32x4*)(fb1 + ocb + t*16 + quad*4);
    #pragma unroll 2
    for (int kc = 0; kc < 36; ++kc){
      short8 b = *(const short8*)(&sG[l15*KST + kc*32 + quad*8]);
      #pragma unroll
      for (int t = 0; t < 4; ++t){
        short8 a = *(const short8*)((const unsigned short*)wT + ((size_t)kc*256 + ocb + t*16 + l15)*32 + quad*8);
        acc[t] = __builtin_amdgcn_mfma_f32_16x16x32_bf16(a, b, acc[t], 0, 0, 0);
      }
    }
    // phase 3: relu -> bf16 -> h1L [cell][oc] stride 264
    #pragma unroll
    for (int t = 0; t < 4; ++t){
      f32x4 v = acc[t];
      uint2 pk;
      pk.x = pack2bf(fmaxf(v[0],0.f), fmaxf(v[1],0.f));
      pk.y = pack2bf(fmaxf(v[2],0.f), fmaxf(v[3],0.f));
      *(uint2*)(&h1L[l15*264 + ocb + t*16 + quad*4]) = pk;
    }
  }
  __syncthreads();

  // phase 4: FC2 MFMA (256 -> 128); wave owns oc [wave*32, wave*32+32)
  {
    const int och = wave*32;
    f32x4 acc2[2];
    #pragma unroll
    for (int t = 0; t < 2; ++t)
      acc2[t] = *(const f32x4*)(fb2 + och + t*16 + quad*4);
    #pragma unroll
    for (int kc = 0; kc < 8; ++kc){
      short8 b = *(const short8*)(&h1L[l15*264 + kc*32 + quad*8]);
      #pragma unroll
      for (int t = 0; t < 2; ++t){
        short8 a = *(const short8*)((const unsigned short*)wT2 + ((size_t)kc*128 + och + t*16 + l15)*32 + quad*8);
        acc2[t] = __builtin_amdgcn_mfma_f32_16x16x32_bf16(a, b, acc2[t], 0, 0, 0);
      }
    }
    // phase 5: relu -> h2L fp32 [cell][oc] stride 132 (overlays sG; sG dead since phase-3 barrier)
    #pragma unroll
    for (int t = 0; t < 2; ++t){
      f32x4 v = acc2[t];
      #pragma unroll
      for (int r = 0; r < 4; ++r) v[r] = fmaxf(v[r], 0.f);
      *(f32x4*)(&h2L[l15*132 + och + t*16 + quad*4]) = v;
    }
  }
  __syncthreads();

  // phase 6: heads (16 cells x 12 outs) + log_prob/entropy/scatter
  if (tid < 192){
    int cell = tid/12, jj = tid - cell*12;
    int which = jj >> 2, o = jj & 3;
    const float* W  = (which==0) ? bw : (which==1 ? iw : tw);
    const float* Bp = (which==0) ? bb : (which==1 ? ib : tb);
    float d = Bp[o];
    const float* h2 = &h2L[cell*132];
    for (int k = 0; k < 128; k++) d += h2[k]*W[k*4+o];
    int cellg = cb + cell;
    if (which == 1){
      out[262147 + cellg*4 + o] = d;
    } else if (which == 2){
      out[262147 + 32768 + cellg*4 + o] = d;
    } else {
      float p = 1.f/(1.f + __expf(-d));
      p = fminf(fmaxf(p, 1e-7f), 1.f - 1e-7f);
      int a = action[cellg*4 + o];
      float lp  = a ? __logf(p) : __logf(1.f-p);
      float ent = -(p*__logf(p) + (1.f-p)*__logf(1.f-p));
      atomicAdd(&sRed[0], lp);
      atomicAdd(&sRed[1], ent);
      if (a){
        const int di[4] = {-1,0,1,0};
        const int dj[4] = {0,1,0,-1};
        int ni = sij[cell] + di[o];
        int nj = sij[16+cell] + dj[o];
        if ((unsigned)ni < 512u && (unsigned)nj < 512u)
          out[ni*512 + nj] = 1.0f;
      }
    }
  }

  // phase 7: global-avg-pool, 1 row per block (512 blocks <-> 512 rows)
  {
    const int gl = tid & 15, xl = tid >> 4;
    float A[8], B[8];
    #pragma unroll
    for (int j = 0; j < 8; ++j){ A[j] = sAB[gl*8+j]; B[j] = sAB[128+gl*8+j]; }
    const int y = blockIdx.x;     // 0..511
    float ps[8] = {0,0,0,0,0,0,0,0};
    for (int x2 = xl; x2 < 512; x2 += 16){
      uint4 v = *(const uint4*)(f + ((size_t)(y+1)*PW + x2+1)*128 + gl*8);
      unsigned uu[4] = {v.x, v.y, v.z, v.w};
      #pragma unroll
      for (int j = 0; j < 4; ++j){
        ps[j*2]   += fmaxf(bflo(uu[j])*A[j*2]   + B[j*2],   0.f);
        ps[j*2+1] += fmaxf(bfhi(uu[j])*A[j*2+1] + B[j*2+1], 0.f);
      }
    }
    #pragma unroll
    for (int j = 0; j < 8; ++j) atomicAdd(&sP[gl*8+j], ps[j]);
  }
  __syncthreads();
  if (tid == 0){
    atomicAdd(&out[262144], sRed[0]);
    atomicAdd(&out[262145], sRed[1]);
  }
  if (tid < 128) atomicAdd(&pooled[tid], sP[tid]);
}

// ---------------- value head MLP ----------------
__global__ void value_kernel(const float* __restrict__ pooled, const float* __restrict__ vw1,
                             const float* __restrict__ vb1, const float* __restrict__ vw2,
                             const float* __restrict__ vb2, float* __restrict__ out){
  int t = threadIdx.x;   // 64 threads
  float h = vb1[t];
  const float invN = 1.f/262144.f;
  for (int c = 0; c < 128; c++) h += (pooled[c]*invN)*vw1[c*64+t];
  h = fmaxf(h, 0.f);
  float v = h*vw2[t];
  #pragma unroll
  for (int off = 32; off; off >>= 1) v += __shfl_xor(v, off);
  if (t == 0) out[262146] = v + vb2[0];
}

extern "C" void kernel_launch(void* const* d_in, const int* in_sizes, int n_in,
                              void* d_out, int out_size, void* d_ws, size_t ws_size,
                              hipStream_t stream) {
  (void)in_sizes; (void)n_in; (void)out_size; (void)ws_size;
  const float* x      = (const float*)d_in[0];
  const int*  cell_i  = (const int*)d_in[1];
  const int*  cell_j  = (const int*)d_in[2];
  const int*  action  = (const int*)d_in[3];
  const float* w1 = (const float*)d_in[4];  const float* b1 = (const float*)d_in[5];
  const float* g1 = (const float*)d_in[6];  const float* be1= (const float*)d_in[7];
  const float* w2 = (const float*)d_in[8];  const float* b2 = (const float*)d_in[9];
  const float* g2 = (const float*)d_in[10]; const float* be2= (const float*)d_in[11];
  const float* w3 = (const float*)d_in[12]; const float* b3 = (const float*)d_in[13];
  const float* g3 = (const float*)d_in[14]; const float* be3= (const float*)d_in[15];
  const float* fw1= (const float*)d_in[16]; const float* fb1= (const float*)d_in[17];
  const float* fw2= (const float*)d_in[18]; const float* fb2= (const float*)d_in[19];
  const float* bw = (const float*)d_in[20]; const float* bb = (const float*)d_in[21];
  const float* iw = (const float*)d_in[22]; const float* ib = (const float*)d_in[23];
  const float* tw = (const float*)d_in[24]; const float* tb = (const float*)d_in[25];
  const float* vw1= (const float*)d_in[26]; const float* vb1= (const float*)d_in[27];
  const float* vw2= (const float*)d_in[28]; const float* vb2= (const float*)d_in[29];

  float* out = (float*)d_out;
  char* ws = (char*)d_ws;
  bf16* buf1 = (bf16*)(ws);                       // 25,362,816 (+small overread slack into buf2)
  bf16* buf2 = (bf16*)(ws + 25362816);            // -> 76,088,448
  bf16* bufF = (bf16*)(ws + 76088448);            // -> 143,722,624
  bf16* wT2  = (bf16*)(ws + 143722624);           // 110,592  -> 143,833,216
  bf16* wT3  = (bf16*)(ws + 143833216);           // 221,184  -> 144,054,400
  bf16* wT1  = (bf16*)(ws + 144054400);           // 15,360   -> 144,069,760
  bf16* wF1T = (bf16*)(ws + 144069760);           // 589,824  -> 144,659,584
  bf16* wF2T = (bf16*)(ws + 144659584);           // 65,536   -> 144,725,120
  float* statsf = (float*)(ws + 144725120);       // 68 floats (L1:0, L2:12, L3:36)
  float* pooled = statsf + 128;                   // 128 floats

  setup_kernel<<<2983, 256, 0, stream>>>(out, statsf, pooled, w1, wT1, w2, wT2, w3, wT3,
                                         fw1, wF1T, fw2, wF2T);
  conv1_mfma_kernel<<<1024, 256, 0, stream>>>(x, wT1, b1, buf1, statsf + 0);
  // conv2: GN(L1)+ReLU fused into LDS staging. 16x16 tile, grid 32x32.
  conv_dma16_kernel<48,2,3,96><<<1024, 256, 0, stream>>>(buf1, wT2, b2, statsf + 0, g1, be1,
                                                         buf2, statsf + 12);
  // conv3: GN(L2)+ReLU fused into LDS staging. 16x8 tile, tri-buffer, grid 32x64.
  conv_dma8_kernel<96,3,2,128,4,8><<<2048, 256, 0, stream>>>(buf2, wT3, b3, statsf + 12, g2, be2,
                                                             bufF, statsf + 36);
  mega_kernel<<<512, 256, 0, stream>>>(bufF, statsf + 36, g3, be3, cell_i, cell_j, action,
                                       wF1T, fb1, wF2T, fb2, bw, bb, iw, ib, tw, tb,
                                       pooled, out);
  value_kernel<<<1, 64, 0, stream>>>(pooled, vw1, vb1, vw2, vb2, out);
}

// Round 9
// 398.081 us; speedup vs baseline: 1.0003x; 1.0003x over previous
//
#include <hip/hip_runtime.h>
#include <hip/hip_bf16.h>
#include <cstddef>

#define NPIX 262144   // 512*512
#define PW 514        // padded width/height
typedef __hip_bfloat16 bf16;
typedef __attribute__((ext_vector_type(8))) short short8;
typedef __attribute__((ext_vector_type(4))) float f32x4;

__device__ inline unsigned short f2bfu(float f){
  __hip_bfloat16 h = __float2bfloat16(f);
  return *(reinterpret_cast<unsigned short*>(&h));
}
__device__ inline float bflo(unsigned u){ return __uint_as_float(u<<16); }
__device__ inline float bfhi(unsigned u){ return __uint_as_float(u & 0xffff0000u); }
// cheap pair pack: round-half-up bf16, low16=a, high16=b (values finite here)
__device__ inline unsigned pack2bf(float a, float b){
  unsigned ua = __float_as_uint(a), ub = __float_as_uint(b);
  return ((ua + 0x8000u) >> 16) | ((ub + 0x8000u) & 0xffff0000u);
}
// async global->LDS 16B DMA (wave-uniform LDS base + lane*16; gptr per-lane)
// HAZARD NOTE (r5/r6 post-mortem): keep the outstanding LDS-DMA queue SHALLOW (<= ~3-6
// instructions/wave, drained by the next __syncthreads within ~1 compute phase). Full
// prefetch of 9 DMAs/wave across a single barrier produced sporadic LDS corruption
// (absmax 0.0078 -> 128) on gfx950 even with a full vmcnt(0) drain. Mechanism unproven;
// do not deepen the queue without a race screen.
// FUSION NOTE (r3/r4/r8): GN+ReLU fusion into conv staging was tried 3 ways (reg-staged x2,
// in-LDS RMW x1). All correct-or-slow: the transform lands on the latency-critical path and
// costs 2-3x what the cheap streaming norm passes cost. Retired -- keep norm_kernel.
__device__ inline void dma16(const bf16* g, unsigned short* l){
  __builtin_amdgcn_global_load_lds(
      (const __attribute__((address_space(1))) unsigned int*)g,
      (__attribute__((address_space(3))) unsigned int*)l, 16, 0, 0);
}

// group-norm affine from accumulated stats (8 channels per group, 262144 px)
__device__ inline void computeAB(const float* stats, const float* gamma, const float* beta,
                                 int c, float& A, float& B){
  int g = c >> 3;
  const float invN = 1.f/2097152.f;
  float m = stats[g*2]*invN;
  float v = stats[g*2+1]*invN - m*m;
  float inv = rsqrtf(v + 1e-5f);
  A = inv*gamma[c];
  B = beta[c] - m*A;
}

// ---------------- merged setup: zero init + all 5 weight transforms ----------------
__global__ void setup_kernel(float* out, float* stats, float* pooled,
                             const float* __restrict__ w1, bf16* __restrict__ wT1,
                             const float* __restrict__ w2, bf16* __restrict__ wT2,
                             const float* __restrict__ w3, bf16* __restrict__ wT3,
                             const float* __restrict__ fw1, bf16* __restrict__ wF1T,
                             const float* __restrict__ fw2, bf16* __restrict__ wF2T){
  int b = blockIdx.x;
  if (b < 1025){
    int i = b*256 + threadIdx.x;
    if (i < 262147) out[i] = 0.f;            // grid + log_prob + entropy + value
    if (i < 68)  stats[i]  = 0.f;
    if (i < 128) pooled[i] = 0.f;
    return;
  }
  b -= 1025;
  if (b < 30){   // conv1 weights: [kc5][oc48][kp32], k = tap*16 + c
    int idx = b*256 + threadIdx.x;
    if (idx < 5*48*32){
      int kp = idx & 31; int oc = (idx >> 5) % 48; int kc = idx / (48*32);
      int k = kc*32 + kp;
      int tap = k >> 4, c = k & 15;
      float v = (tap < 9 && c < 14) ? w1[(oc*14 + c)*9 + tap] : 0.f;
      wT1[idx] = __float2bfloat16(v);
    }
    return;
  }
  b -= 30;
  if (b < 216){  // conv2 weights: [tap][cc2][oc96][cp32] (ic 48..63 zero!)
    int idx = b*256 + threadIdx.x;
    if (idx < 9*2*96*32){
      int cp = idx & 31; int rest = idx >> 5;
      int oc = rest % 96; rest /= 96;
      int cc = rest % 2; int tap = rest / 2;
      int ic = cc*32 + cp;
      float v = (ic < 48) ? w2[(oc*48 + ic)*9 + tap] : 0.f;
      wT2[idx] = __float2bfloat16(v);
    }
    return;
  }
  b -= 216;
  if (b < 432){  // conv3 weights: [tap][cc3][oc128][cp32]
    int idx = b*256 + threadIdx.x;
    if (idx < 9*3*128*32){
      int cp = idx & 31; int rest = idx >> 5;
      int oc = rest & 127; rest >>= 7;
      int cc = rest % 3; int tap = rest / 3;
      int ic = cc*32 + cp;
      float v = (ic < 96) ? w3[(oc*96 + ic)*9 + tap] : 0.f;
      wT3[idx] = __float2bfloat16(v);
    }
    return;
  }
  b -= 432;
  if (b < 1152){ // fc1 weights: [kc36][oc256][kp32], k' = rr*128 + ch (tap-major)
    int idx = b*256 + threadIdx.x;
    if (idx < 36*256*32){
      int kp = idx & 31; int oc = (idx >> 5) & 255; int kc = idx >> 13;
      int k2 = kc*32 + kp;
      int rr = k2 >> 7, ch = k2 & 127;
      wF1T[idx] = __float2bfloat16(fw1[(size_t)(ch*9 + rr)*256 + oc]);
    }
    return;
  }
  b -= 1152;
  {              // fc2 weights: [kc8][oc128][kp32]
    int idx = b*256 + threadIdx.x;
    if (idx < 8*128*32){
      int kp = idx & 31; int oc = (idx >> 5) & 127; int kc = idx >> 12;
      wF2T[idx] = __float2bfloat16(fw2[(size_t)(kc*32 + kp)*128 + oc]);
    }
  }
}

// ---------------- conv1 MFMA: 14ch fp32 NCHW -> 48ch raw bf16 padded NHWC, + stats ----------------
__launch_bounds__(256,2)
__global__ void conv1_mfma_kernel(const float* __restrict__ x, const bf16* __restrict__ wT,
                                  const float* __restrict__ bias, bf16* __restrict__ out,
                                  float* __restrict__ stats){
  constexpr int XP = 24;
  __shared__ unsigned short sX[324*XP];
  __shared__ float sStat[96];
  const int tid = threadIdx.x;
  const int lane = tid & 63, wave = tid >> 6;
  const int quad = lane >> 4, l15 = lane & 15;
  const int tileX = (blockIdx.x & 31)*16, tileY = (blockIdx.x >> 5)*16;
  if (tid < 96) sStat[tid] = 0.f;
  for (int p = tid; p < 324; p += 256){ sX[p*XP+14] = 0; sX[p*XP+15] = 0; }
  for (int idx = tid; idx < 14*324; idx += 256){
    int c = idx / 324, p = idx - c*324;
    int r = p / 18, col = p - r*18;
    int gy = tileY + r - 1, gx = tileX + col - 1;
    float v = 0.f;
    if ((unsigned)gy < 512u && (unsigned)gx < 512u) v = x[(size_t)c*NPIX + gy*512 + gx];
    sX[p*XP + c] = f2bfu(v);
  }
  __syncthreads();

  f32x4 acc[3][4];
  #pragma unroll
  for (int t = 0; t < 3; ++t){
    f32x4 bv = *(const f32x4*)(bias + t*16 + quad*4);
    #pragma unroll
    for (int s = 0; s < 4; ++s) acc[t][s] = bv;
  }
  const int pxb = wave*4;
  const int h = quad >> 1, chalf = (quad & 1)*8;
  const int T0[5] = {0,2,4,6,8};
  const int T1[5] = {1,3,5,7,8};
  #pragma unroll
  for (int kc = 0; kc < 5; ++kc){
    short8 a[3];
    #pragma unroll
    for (int t = 0; t < 3; ++t)
      a[t] = *(const short8*)((const unsigned short*)wT + (size_t)(kc*48 + t*16 + l15)*32 + quad*8);
    const int ky = h ? (T1[kc]/3) : (T0[kc]/3);
    const int kx = h ? (T1[kc]%3) : (T0[kc]%3);
    #pragma unroll
    for (int s = 0; s < 4; ++s){
      int py = pxb + s;
      short8 bfr = *(const short8*)(&sX[((py+ky)*18 + l15+kx)*XP + chalf]);
      #pragma unroll
      for (int t = 0; t < 3; ++t)
        acc[t][s] = __builtin_amdgcn_mfma_f32_16x16x32_bf16(a[t], bfr, acc[t][s], 0, 0, 0);
    }
  }
  #pragma unroll
  for (int t = 0; t < 3; ++t){
    #pragma unroll
    for (int r = 0; r < 4; ++r){
      float sv = 0.f, sq = 0.f;
      #pragma unroll
      for (int s = 0; s < 4; ++s){ float v = acc[t][s][r]; sv += v; sq += v*v; }
      #pragma unroll
      for (int m = 1; m < 16; m <<= 1){ sv += __shfl_xor(sv, m); sq += __shfl_xor(sq, m); }
      if (l15 == 0){
        atomicAdd(&sStat[(t*16 + quad*4 + r)*2],   sv);
        atomicAdd(&sStat[(t*16 + quad*4 + r)*2+1], sq);
      }
    }
    #pragma unroll
    for (int s = 0; s < 4; ++s){
      f32x4 v = acc[t][s];
      uint2 pk;
      pk.x = pack2bf(v[0], v[1]);
      pk.y = pack2bf(v[2], v[3]);
      *(uint2*)(out + ((size_t)(tileY+pxb+s+1)*PW + tileX+l15+1)*48 + t*16 + quad*4) = pk;
    }
  }
  __syncthreads();
  if (tid < 12){
    int g = tid >> 1, wsel = tid & 1;
    float v = 0.f;
    #pragma unroll
    for (int j = 0; j < 8; ++j) v += sStat[(g*8+j)*2 + wsel];
    atomicAdd(&stats[g*2 + wsel], v);
  }
}

// ---------------- in-place GN+ReLU (interior) + zero borders; 4 blocks per row ----------------
template<int C>
__global__ void norm_kernel(bf16* buf, const float* __restrict__ stats,
                            const float* __restrict__ gamma, const float* __restrict__ beta){
  __shared__ float sAB[2*C];
  const int tid = threadIdx.x;
  if (tid < C){ float A,B; computeAB(stats, gamma, beta, tid, A, B); sAB[tid]=A; sAB[C+tid]=B; }
  __syncthreads();
  const int y = blockIdx.x >> 2, q = blockIdx.x & 3;   // y 0..513
  uint4* row = (uint4*)(buf + (size_t)y*PW*C);
  constexpr int NU4 = PW*C/8/4;      // per-quarter uint4 count (divisible for C=48,96)
  const bool brow = (y == 0) | (y == 513);
  for (int i = q*NU4 + tid; i < (q+1)*NU4; i += 256){
    int e = i*8;
    int px = e / C;
    if (brow | (px == 0) | (px == 513)){ row[i] = make_uint4(0,0,0,0); continue; }
    int ch = e - px*C;
    uint4 v = row[i];
    unsigned uu[4] = {v.x,v.y,v.z,v.w}, ou[4];
    #pragma unroll
    for (int j = 0; j < 4; ++j){
      float a = fmaxf(bflo(uu[j])*sAB[ch+j*2]   + sAB[C+ch+j*2],   0.f);
      float d = fmaxf(bfhi(uu[j])*sAB[ch+j*2+1] + sAB[C+ch+j*2+1], 0.f);
      ou[j] = pack2bf(a, d);
    }
    row[i] = make_uint4(ou[0],ou[1],ou[2],ou[3]);
  }
}

// ---------------- conv2: 16x16-tile MFMA conv, shallow double-buffered DMA (r0-verified) ----
// LDS slot (row,cc,col) = (row*4+cc)*18 + col (16B each); b-frag ds_read = one base + imm offset.
template<int IC, int NCC, int OCT, int OC>
__launch_bounds__(256, 2)
__global__ void conv_dma16_kernel(const bf16* __restrict__ in, const bf16* __restrict__ wT,
                                  const float* __restrict__ bias,
                                  bf16* __restrict__ out, float* __restrict__ outstats){
  __shared__ unsigned short sIn[2][1296*8];   // 2 x 20736 B
  __shared__ float sStat[2*OC];
  const int tid  = threadIdx.x;
  const int lane = tid & 63, wave = tid >> 6;
  const int quad = lane >> 4, l15 = lane & 15;
  const int ocg = wave >> 1, pxg = wave & 1;
  const int tileX = (blockIdx.x & 31) * 16, tileY = (blockIdx.x >> 5) * 16;
  const int ocbase = ocg * (OCT*16);

  for (int i = tid; i < 2*OC; i += 256) sStat[i] = 0.f;

  // per-thread DMA source offsets, computed ONCE (chunk adds cr*32 elements)
  unsigned off[6];
  #pragma unroll
  for (int k = 0; k < 6; ++k){
    int slot = tid + k*256;
    if (k < 5 || tid < 16){
      int row = slot/72; int rem = slot - row*72;
      int cc = rem/18;   int col = rem - cc*18;
      // for IC=48, chunk 1 cc>=2 reads past-channel (finite) data; weights are 0 there.
      off[k] = (unsigned)(((tileY+row)*PW + tileX+col)*IC + cc*8);
    }
  }
  auto issueDMA = [&](int cr, int bi){
    #pragma unroll
    for (int k = 0; k < 6; ++k){
      if (k == 5 && tid >= 16) continue;
      dma16(in + off[k] + cr*32, &sIn[bi][(tid + k*256)*8]);
    }
  };

  f32x4 acc[OCT][8];
  #pragma unroll
  for (int t = 0; t < OCT; ++t){
    f32x4 bv = *(const f32x4*)(bias + ocbase + t*16 + quad*4);
    #pragma unroll
    for (int s = 0; s < 8; ++s) acc[t][s] = bv;
  }

  issueDMA(0, 0);
  __syncthreads();               // drains DMA(0); sStat ready

  #pragma unroll 1
  for (int cr = 0; cr < NCC; ++cr){
    // wave-shared b base: all tap/s offsets are compile-time immediates from here
    const unsigned short* B0 = &sIn[cr & 1][(((pxg*8)*4 + quad)*18 + l15)*8];
    const unsigned short* W0 = (const unsigned short*)wT + ((size_t)cr*OC + ocbase + l15)*32 + quad*8;

    #pragma unroll
    for (int tap = 0; tap < 9; ++tap){
      if (tap == 7 && cr + 1 < NCC) issueDMA(cr + 1, (cr + 1) & 1);
      const int ky = tap/3, kx = tap - ky*3;
      short8 a[OCT];
      #pragma unroll
      for (int t = 0; t < OCT; ++t)
        a[t] = *(const short8*)(W0 + (size_t)tap*(NCC*OC*32) + t*512);
      #pragma unroll
      for (int s = 0; s < 8; ++s){
        short8 b = *(const short8*)(B0 + ((s+ky)*72 + kx)*8);
        #pragma unroll
        for (int t = 0; t < OCT; ++t)
          acc[t][s] = __builtin_amdgcn_mfma_f32_16x16x32_bf16(a[t], b, acc[t][s], 0, 0, 0);
      }
    }
    __syncthreads();             // all waves done with this buffer; next DMA drained
  }

  // stats + store raw bf16
  #pragma unroll
  for (int t = 0; t < OCT; ++t){
    #pragma unroll
    for (int r = 0; r < 4; ++r){
      float sv = 0.f, sq = 0.f;
      #pragma unroll
      for (int s = 0; s < 8; ++s){ float v = acc[t][s][r]; sv += v; sq += v*v; }
      #pragma unroll
      for (int m = 1; m < 16; m <<= 1){ sv += __shfl_xor(sv, m); sq += __shfl_xor(sq, m); }
      if (l15 == 0){
        atomicAdd(&sStat[(ocbase + t*16 + quad*4 + r)*2],   sv);
        atomicAdd(&sStat[(ocbase + t*16 + quad*4 + r)*2+1], sq);
      }
    }
    #pragma unroll
    for (int s = 0; s < 8; ++s){
      int py = pxg*8 + s;
      f32x4 v = acc[t][s];
      uint2 pk;
      pk.x = pack2bf(v[0], v[1]);
      pk.y = pack2bf(v[2], v[3]);
      *(uint2*)(out + ((size_t)(tileY+py+1)*PW + (tileX+l15+1))*OC + ocbase + t*16 + quad*4) = pk;
    }
  }
  __syncthreads();
  if (tid < (OC/8)*2){
    int g = tid >> 1, wsel = tid & 1;
    float v = 0.f;
    #pragma unroll
    for (int j = 0; j < 8; ++j) v += sStat[(g*8+j)*2 + wsel];
    atomicAdd(&outstats[g*2 + wsel], v);
  }
}

// ---------------- conv3: 16xTH-tile MFMA conv, r-major taps, shallow double buffer ----------------
// r7-verified template; TH=4 this round: halves acc (64->32 AGPR) -> 4 waves/SIMD (was 3),
// grid doubles to 32x128. More resident waves on a latency-bound kernel; +20% halo fetch
// (HBM at 15% has headroom). Schedule/DMA depth unchanged (K outstanding, drained within
// one compute phase -- r5/r6 hazard respected).
template<int IC, int NCC, int OCT, int OC, int NW, int TH, int MINW>
__launch_bounds__(NW*64, MINW)
__global__ void conv_dma8_kernel(const bf16* __restrict__ in, const bf16* __restrict__ wT,
                                 const float* __restrict__ bias,
                                 bf16* __restrict__ out, float* __restrict__ outstats){
  constexpr int NT   = NW*64;
  constexpr int ROWS = TH + 2;
  constexpr int SLOTS = ROWS * 72;              // 16B slots per chunk
  constexpr int K    = (SLOTS + NT - 1) / NT;
  constexpr int REM  = SLOTS - (K-1)*NT;        // active threads in last k
  __shared__ unsigned short sIn[2][SLOTS*8];
  __shared__ float sStat[2*OC];
  const int tid  = threadIdx.x;
  const int lane = tid & 63, wave = tid >> 6;
  const int quad = lane >> 4, l15 = lane & 15;
  const int tileX = (blockIdx.x & 31) * 16, tileY = (blockIdx.x >> 5) * TH;
  const int ocbase = wave * (OCT*16);

  for (int i = tid; i < 2*OC; i += NT) sStat[i] = 0.f;

  // per-thread DMA source offsets, computed ONCE (chunk adds cr*32 elements)
  unsigned off[K];
  #pragma unroll
  for (int k = 0; k < K; ++k){
    int slot = tid + k*NT;
    if (k < K-1 || tid < REM){
      int row = slot/72; int rem = slot - row*72;
      int cc = rem/18;   int col = rem - cc*18;
      off[k] = (unsigned)(((tileY+row)*PW + tileX+col)*IC + cc*8);
    }
  }
  auto issueDMA = [&](int cr, int bi){
    #pragma unroll
    for (int k = 0; k < K; ++k){
      if (k == K-1 && tid >= REM) continue;
      dma16(in + off[k] + cr*32, &sIn[bi][(tid + k*NT)*8]);
    }
  };

  f32x4 acc[OCT][TH];
  #pragma unroll
  for (int t = 0; t < OCT; ++t){
    f32x4 bv = *(const f32x4*)(bias + ocbase + t*16 + quad*4);
    #pragma unroll
    for (int s = 0; s < TH; ++s) acc[t][s] = bv;
  }

  issueDMA(0, 0);
  __syncthreads();               // drains DMA(0); sStat ready

  #pragma unroll 1
  for (int cr = 0; cr < NCC; ++cr){
    if (cr + 1 < NCC) issueDMA(cr + 1, (cr + 1) & 1);   // buffer free since last barrier
    // wave-shared b base: all row/kx offsets are compile-time immediates from here
    const unsigned short* B0 = &sIn[cr & 1][(quad*18 + l15)*8];
    const unsigned short* W0 = (const unsigned short*)wT + ((size_t)cr*OC + ocbase + l15)*32 + quad*8;

    #pragma unroll
    for (int kx = 0; kx < 3; ++kx){
      short8 a[3][OCT];
      #pragma unroll
      for (int ky = 0; ky < 3; ++ky)
        #pragma unroll
        for (int t = 0; t < OCT; ++t)
          a[ky][t] = *(const short8*)(W0 + (size_t)(ky*3+kx)*(NCC*OC*32) + t*512);
      #pragma unroll
      for (int r = 0; r < ROWS; ++r){
        short8 b = *(const short8*)(B0 + (r*72 + kx)*8);
        #pragma unroll
        for (int ky = 0; ky < 3; ++ky){
          const int s = r - ky;
          if (s >= 0 && s < TH){
            #pragma unroll
            for (int t = 0; t < OCT; ++t)
              acc[t][s] = __builtin_amdgcn_mfma_f32_16x16x32_bf16(a[ky][t], b, acc[t][s], 0, 0, 0);
          }
        }
      }
    }
    __syncthreads();             // all waves done with this buffer; next DMA drained
  }

  // stats + store raw bf16
  #pragma unroll
  for (int t = 0; t < OCT; ++t){
    #pragma unroll
    for (int r = 0; r < 4; ++r){
      float sv = 0.f, sq = 0.f;
      #pragma unroll
      for (int s = 0; s < TH; ++s){ float v = acc[t][s][r]; sv += v; sq += v*v; }
      #pragma unroll
      for (int m = 1; m < 16; m <<= 1){ sv += __shfl_xor(sv, m); sq += __shfl_xor(sq, m); }
      if (l15 == 0){
        atomicAdd(&sStat[(ocbase + t*16 + quad*4 + r)*2],   sv);
        atomicAdd(&sStat[(ocbase + t*16 + quad*4 + r)*2+1], sq);
      }
    }
    #pragma unroll
    for (int s = 0; s < TH; ++s){
      f32x4 v = acc[t][s];
      uint2 pk;
      pk.x = pack2bf(v[0], v[1]);
      pk.y = pack2bf(v[2], v[3]);
      *(uint2*)(out + ((size_t)(tileY+s+1)*PW + (tileX+l15+1))*OC + ocbase + t*16 + quad*4) = pk;
    }
  }
  __syncthreads();
  if (tid < (OC/8)*2){
    int g = tid >> 1, wsel = tid & 1;
    float v = 0.f;
    #pragma unroll
    for (int j = 0; j < 8; ++j) v += sStat[(g*8+j)*2 + wsel];
    atomicAdd(&outstats[g*2 + wsel], v);
  }
}

// ---------------- MEGA: gather+GN+ReLU -> FC1(MFMA) -> FC2(MFMA) -> heads ->
//                  log_prob/entropy/scatter, plus 1 pool row per block. 512 blocks x 16 cells. ----
__launch_bounds__(256)
__global__ void mega_kernel(const bf16* __restrict__ f, const float* __restrict__ instats,
                            const float* __restrict__ gamma, const float* __restrict__ beta,
                            const int* __restrict__ cell_i, const int* __restrict__ cell_j,
                            const int* __restrict__ action,
                            const bf16* __restrict__ wT, const float* __restrict__ fb1,
                            const bf16* __restrict__ wT2, const float* __restrict__ fb2,
                            const float* __restrict__ bw, const float* __restrict__ bb,
                            const float* __restrict__ iw, const float* __restrict__ ib,
                            const float* __restrict__ tw, const float* __restrict__ tb,
                            float* __restrict__ pooled, float* __restrict__ out){
  constexpr int KST = 1160;               // fc1 k stride (shorts)
  __shared__ unsigned short sG[16*KST];   // 37120 B; overlaid by h2L after FC1 reads done
  __shared__ unsigned short h1L[16*264];  // 8448 B
  __shared__ float sAB[256];
  __shared__ int sij[32];
  __shared__ float sRed[2];
  __shared__ float sP[128];
  float* h2L = (float*)sG;                // 16*132 fp32 = 8448 B (inside sG)
  const int tid = threadIdx.x;
  const int lane = tid & 63, wave = tid >> 6;
  const int quad = lane >> 4, l15 = lane & 15;
  const int cb = blockIdx.x*16;

  if (tid < 2) sRed[tid] = 0.f;
  if (tid < 128){ float A,B; computeAB(instats, gamma, beta, tid, A, B);
    sAB[tid]=A; sAB[128+tid]=B; sP[tid]=0.f; }
  if (tid < 16) sij[tid] = cell_i[cb + tid];
  else if (tid < 32) sij[tid] = cell_j[cb + tid - 16];
  __syncthreads();

  // phase 1: gather 16 cells' 3x3x128 patches (GN+ReLU) -> sG [cell][k'=rr*128+ch]
  for (int idx = tid; idx < 16*144; idx += 256){
    int c8 = idx & 15; int t2 = idx >> 4;
    int cell = t2 / 9, rr = t2 - cell*9;
    int r = rr/3, cl = rr - r*3;
    int py = sij[cell] + r, px = sij[16+cell] + cl;   // padded coords
    uint4 v = *(const uint4*)(f + ((size_t)py*PW + px)*128 + c8*8);
    bool border = (py==0) | (py==513) | (px==0) | (px==513);
    unsigned uu[4] = {v.x, v.y, v.z, v.w};
    unsigned ou[4];
    #pragma unroll
    for (int j = 0; j < 4; ++j){
      int ch = c8*8 + j*2;
      float a = border ? 0.f : fmaxf(bflo(uu[j])*sAB[ch]   + sAB[128+ch],   0.f);
      float d = border ? 0.f : fmaxf(bfhi(uu[j])*sAB[ch+1] + sAB[128+ch+1], 0.f);
      ou[j] = pack2bf(a, d);
    }
    uint4 wv; wv.x = ou[0]; wv.y = ou[1]; wv.z = ou[2]; wv.w = ou[3];
    *(uint4*)(&sG[cell*KST + rr*128 + c8*8]) = wv;
  }
  __syncthreads();

  // phase 2: FC1 MFMA (1152 -> 256), wave owns oc [wave*64, wave*64+64)
  {
    f32x4 acc[4];
    const int ocb = wave*64;
    #pragma unroll
    for (int t = 0; t < 4; ++t)
      acc[t] = *(const f32x4*)(fb1 + ocb + t*16 + quad*4);
    #pragma unroll 2
    for (int kc = 0; kc < 36; ++kc){
      short8 b = *(const short8*)(&sG[l15*KST + kc*32 + quad*8]);
      #pragma unroll
      for (int t = 0; t < 4; ++t){
        short8 a = *(const short8*)((const unsigned short*)wT + ((size_t)kc*256 + ocb + t*16 + l15)*32 + quad*8);
        acc[t] = __builtin_amdgcn_mfma_f32_16x16x32_bf16(a, b, acc[t], 0, 0, 0);
      }
    }
    // phase 3: relu -> bf16 -> h1L [cell][oc] stride 264
    #pragma unroll
    for (int t = 0; t < 4; ++t){
      f32x4 v = acc[t];
      uint2 pk;
      pk.x = pack2bf(fmaxf(v[0],0.f), fmaxf(v[1],0.f));
      pk.y = pack2bf(fmaxf(v[2],0.f), fmaxf(v[3],0.f));
      *(uint2*)(&h1L[l15*264 + ocb + t*16 + quad*4]) = pk;
    }
  }
  __syncthreads();

  // phase 4: FC2 MFMA (256 -> 128); wave owns oc [wave*32, wave*32+32)
  {
    const int och = wave*32;
    f32x4 acc2[2];
    #pragma unroll
    for (int t = 0; t < 2; ++t)
      acc2[t] = *(const f32x4*)(fb2 + och + t*16 + quad*4);
    #pragma unroll
    for (int kc = 0; kc < 8; ++kc){
      short8 b = *(const short8*)(&h1L[l15*264 + kc*32 + quad*8]);
      #pragma unroll
      for (int t = 0; t < 2; ++t){
        short8 a = *(const short8*)((const unsigned short*)wT2 + ((size_t)kc*128 + och + t*16 + l15)*32 + quad*8);
        acc2[t] = __builtin_amdgcn_mfma_f32_16x16x32_bf16(a, b, acc2[t], 0, 0, 0);
      }
    }
    // phase 5: relu -> h2L fp32 [cell][oc] stride 132 (overlays sG; sG dead since phase-3 barrier)
    #pragma unroll
    for (int t = 0; t < 2; ++t){
      f32x4 v = acc2[t];
      #pragma unroll
      for (int r = 0; r < 4; ++r) v[r] = fmaxf(v[r], 0.f);
      *(f32x4*)(&h2L[l15*132 + och + t*16 + quad*4]) = v;
    }
  }
  __syncthreads();

  // phase 6: heads (16 cells x 12 outs) + log_prob/entropy/scatter
  if (tid < 192){
    int cell = tid/12, jj = tid - cell*12;
    int which = jj >> 2, o = jj & 3;
    const float* W  = (which==0) ? bw : (which==1 ? iw : tw);
    const float* Bp = (which==0) ? bb : (which==1 ? ib : tb);
    float d = Bp[o];
    const float* h2 = &h2L[cell*132];
    for (int k = 0; k < 128; k++) d += h2[k]*W[k*4+o];
    int cellg = cb + cell;
    if (which == 1){
      out[262147 + cellg*4 + o] = d;
    } else if (which == 2){
      out[262147 + 32768 + cellg*4 + o] = d;
    } else {
      float p = 1.f/(1.f + __expf(-d));
      p = fminf(fmaxf(p, 1e-7f), 1.f - 1e-7f);
      int a = action[cellg*4 + o];
      float lp  = a ? __logf(p) : __logf(1.f-p);
      float ent = -(p*__logf(p) + (1.f-p)*__logf(1.f-p));
      atomicAdd(&sRed[0], lp);
      atomicAdd(&sRed[1], ent);
      if (a){
        const int di[4] = {-1,0,1,0};
        const int dj[4] = {0,1,0,-1};
        int ni = sij[cell] + di[o];
        int nj = sij[16+cell] + dj[o];
        if ((unsigned)ni < 512u && (unsigned)nj < 512u)
          out[ni*512 + nj] = 1.0f;
      }
    }
  }

  // phase 7: global-avg-pool, 1 row per block (512 blocks <-> 512 rows)
  {
    const int gl = tid & 15, xl = tid >> 4;
    float A[8], B[8];
    #pragma unroll
    for (int j = 0; j < 8; ++j){ A[j] = sAB[gl*8+j]; B[j] = sAB[128+gl*8+j]; }
    const int y = blockIdx.x;     // 0..511
    float ps[8] = {0,0,0,0,0,0,0,0};
    for (int x2 = xl; x2 < 512; x2 += 16){
      uint4 v = *(const uint4*)(f + ((size_t)(y+1)*PW + x2+1)*128 + gl*8);
      unsigned uu[4] = {v.x, v.y, v.z, v.w};
      #pragma unroll
      for (int j = 0; j < 4; ++j){
        ps[j*2]   += fmaxf(bflo(uu[j])*A[j*2]   + B[j*2],   0.f);
        ps[j*2+1] += fmaxf(bfhi(uu[j])*A[j*2+1] + B[j*2+1], 0.f);
      }
    }
    #pragma unroll
    for (int j = 0; j < 8; ++j) atomicAdd(&sP[gl*8+j], ps[j]);
  }
  __syncthreads();
  if (tid == 0){
    atomicAdd(&out[262144], sRed[0]);
    atomicAdd(&out[262145], sRed[1]);
  }
  if (tid < 128) atomicAdd(&pooled[tid], sP[tid]);
}

// ---------------- value head MLP ----------------
__global__ void value_kernel(const float* __restrict__ pooled, const float* __restrict__ vw1,
                             const float* __restrict__ vb1, const float* __restrict__ vw2,
                             const float* __restrict__ vb2, float* __restrict__ out){
  int t = threadIdx.x;   // 64 threads
  float h = vb1[t];
  const float invN = 1.f/262144.f;
  for (int c = 0; c < 128; c++) h += (pooled[c]*invN)*vw1[c*64+t];
  h = fmaxf(h, 0.f);
  float v = h*vw2[t];
  #pragma unroll
  for (int off = 32; off; off >>= 1) v += __shfl_xor(v, off);
  if (t == 0) out[262146] = v + vb2[0];
}

extern "C" void kernel_launch(void* const* d_in, const int* in_sizes, int n_in,
                              void* d_out, int out_size, void* d_ws, size_t ws_size,
                              hipStream_t stream) {
  (void)in_sizes; (void)n_in; (void)out_size; (void)ws_size;
  const float* x      = (const float*)d_in[0];
  const int*  cell_i  = (const int*)d_in[1];
  const int*  cell_j  = (const int*)d_in[2];
  const int*  action  = (const int*)d_in[3];
  const float* w1 = (const float*)d_in[4];  const float* b1 = (const float*)d_in[5];
  const float* g1 = (const float*)d_in[6];  const float* be1= (const float*)d_in[7];
  const float* w2 = (const float*)d_in[8];  const float* b2 = (const float*)d_in[9];
  const float* g2 = (const float*)d_in[10]; const float* be2= (const float*)d_in[11];
  const float* w3 = (const float*)d_in[12]; const float* b3 = (const float*)d_in[13];
  const float* g3 = (const float*)d_in[14]; const float* be3= (const float*)d_in[15];
  const float* fw1= (const float*)d_in[16]; const float* fb1= (const float*)d_in[17];
  const float* fw2= (const float*)d_in[18]; const float* fb2= (const float*)d_in[19];
  const float* bw = (const float*)d_in[20]; const float* bb = (const float*)d_in[21];
  const float* iw = (const float*)d_in[22]; const float* ib = (const float*)d_in[23];
  const float* tw = (const float*)d_in[24]; const float* tb = (const float*)d_in[25];
  const float* vw1= (const float*)d_in[26]; const float* vb1= (const float*)d_in[27];
  const float* vw2= (const float*)d_in[28]; const float* vb2= (const float*)d_in[29];

  float* out = (float*)d_out;
  char* ws = (char*)d_ws;
  bf16* buf1 = (bf16*)(ws);                       // 25,362,816 (+small overread slack into buf2)
  bf16* buf2 = (bf16*)(ws + 25362816);            // -> 76,088,448
  bf16* bufF = (bf16*)(ws + 76088448);            // -> 143,722,624
  bf16* wT2  = (bf16*)(ws + 143722624);           // 110,592  -> 143,833,216
  bf16* wT3  = (bf16*)(ws + 143833216);           // 221,184  -> 144,054,400
  bf16* wT1  = (bf16*)(ws + 144054400);           // 15,360   -> 144,069,760
  bf16* wF1T = (bf16*)(ws + 144069760);           // 589,824  -> 144,659,584
  bf16* wF2T = (bf16*)(ws + 144659584);           // 65,536   -> 144,725,120
  float* statsf = (float*)(ws + 144725120);       // 68 floats (L1:0, L2:12, L3:36)
  float* pooled = statsf + 128;                   // 128 floats

  setup_kernel<<<2983, 256, 0, stream>>>(out, statsf, pooled, w1, wT1, w2, wT2, w3, wT3,
                                         fw1, wF1T, fw2, wF2T);
  conv1_mfma_kernel<<<1024, 256, 0, stream>>>(x, wT1, b1, buf1, statsf + 0);
  norm_kernel<48><<<514*4, 256, 0, stream>>>(buf1, statsf + 0, g1, be1);
  // conv2: r0-verified 16x16 tile, 4 waves (2 ocg x 48 oc), grid 32x32
  conv_dma16_kernel<48,2,3,96><<<1024, 256, 0, stream>>>(buf1, wT2, b2, buf2, statsf + 12);
  norm_kernel<96><<<514*4, 256, 0, stream>>>(buf2, statsf + 12, g2, be2);
  // conv3: verified template, TH=4 (32 AGPR acc -> 4 waves/SIMD), grid 32x128
  conv_dma8_kernel<96,3,2,128,4,4,4><<<4096, 256, 0, stream>>>(buf2, wT3, b3, bufF, statsf + 36);
  mega_kernel<<<512, 256, 0, stream>>>(bufF, statsf + 36, g3, be3, cell_i, cell_j, action,
                                       wF1T, fb1, wF2T, fb2, bw, bb, iw, ib, tw, tb,
                                       pooled, out);
  value_kernel<<<1, 64, 0, stream>>>(pooled, vw1, vb1, vw2, vb2, out);
}

// Round 11
// 356.203 us; speedup vs baseline: 1.1179x; 1.1176x over previous
//
#include <hip/hip_runtime.h>
#include <hip/hip_bf16.h>
#include <cstddef>

#define NPIX 262144   // 512*512
#define PW 514        // padded width/height
typedef __hip_bfloat16 bf16;
typedef __attribute__((ext_vector_type(8))) short short8;
typedef __attribute__((ext_vector_type(4))) float f32x4;

__device__ inline unsigned short f2bfu(float f){
  __hip_bfloat16 h = __float2bfloat16(f);
  return *(reinterpret_cast<unsigned short*>(&h));
}
__device__ inline float bflo(unsigned u){ return __uint_as_float(u<<16); }
__device__ inline float bfhi(unsigned u){ return __uint_as_float(u & 0xffff0000u); }
// cheap pair pack: round-half-up bf16, low16=a, high16=b (values finite here)
__device__ inline unsigned pack2bf(float a, float b){
  unsigned ua = __float_as_uint(a), ub = __float_as_uint(b);
  return ((ua + 0x8000u) >> 16) | ((ub + 0x8000u) & 0xffff0000u);
}
// async global->LDS 16B DMA (wave-uniform LDS base + lane*16; gptr per-lane)
// HAZARD NOTE (r5/r6): keep the outstanding LDS-DMA queue SHALLOW (<= ~3-6 per wave,
// drained by the next __syncthreads within ~1 compute phase). 8-9 outstanding across one
// barrier corrupted LDS sporadically (absmax 0.0078 -> 128) even with full vmcnt(0) drain.
// FUSION NOTE (r3/r4/r8): GN+ReLU fusion into conv staging retired (3 attempts, all slow).
// OCCUPANCY NOTE (r9): TH=4 raised occupancy 27->37% but SLOWED conv3 (+20%): limiter is
// per-block barrier/drain critical path, not wave count. TH=8 / 3 waves/SIMD is optimal here.
__device__ inline void dma16(const bf16* g, unsigned short* l){
  __builtin_amdgcn_global_load_lds(
      (const __attribute__((address_space(1))) unsigned int*)g,
      (__attribute__((address_space(3))) unsigned int*)l, 16, 0, 0);
}

// group-norm affine from accumulated stats (8 channels per group, 262144 px)
__device__ inline void computeAB(const float* stats, const float* gamma, const float* beta,
                                 int c, float& A, float& B){
  int g = c >> 3;
  const float invN = 1.f/2097152.f;
  float m = stats[g*2]*invN;
  float v = stats[g*2+1]*invN - m*m;
  float inv = rsqrtf(v + 1e-5f);
  A = inv*gamma[c];
  B = beta[c] - m*A;
}

// ---------------- merged setup: zero init + all 5 weight transforms ----------------
__global__ void setup_kernel(float* out, float* stats, float* pooled,
                             const float* __restrict__ w1, bf16* __restrict__ wT1,
                             const float* __restrict__ w2, bf16* __restrict__ wT2,
                             const float* __restrict__ w3, bf16* __restrict__ wT3,
                             const float* __restrict__ fw1, bf16* __restrict__ wF1T,
                             const float* __restrict__ fw2, bf16* __restrict__ wF2T){
  int b = blockIdx.x;
  if (b < 1025){
    int i = b*256 + threadIdx.x;
    if (i < 262147) out[i] = 0.f;            // grid + log_prob + entropy + value
    if (i < 68)  stats[i]  = 0.f;
    if (i < 128) pooled[i] = 0.f;
    return;
  }
  b -= 1025;
  if (b < 30){   // conv1 weights: [kc5][oc48][kp32], k = tap*16 + c
    int idx = b*256 + threadIdx.x;
    if (idx < 5*48*32){
      int kp = idx & 31; int oc = (idx >> 5) % 48; int kc = idx / (48*32);
      int k = kc*32 + kp;
      int tap = k >> 4, c = k & 15;
      float v = (tap < 9 && c < 14) ? w1[(oc*14 + c)*9 + tap] : 0.f;
      wT1[idx] = __float2bfloat16(v);
    }
    return;
  }
  b -= 30;
  if (b < 216){  // conv2 weights: [tap][cc2][oc96][cp32] (ic 48..63 zero!)
    int idx = b*256 + threadIdx.x;
    if (idx < 9*2*96*32){
      int cp = idx & 31; int rest = idx >> 5;
      int oc = rest % 96; rest /= 96;
      int cc = rest % 2; int tap = rest / 2;
      int ic = cc*32 + cp;
      float v = (ic < 48) ? w2[(oc*48 + ic)*9 + tap] : 0.f;
      wT2[idx] = __float2bfloat16(v);
    }
    return;
  }
  b -= 216;
  if (b < 432){  // conv3 weights: [tap][cc3][oc128][cp32]
    int idx = b*256 + threadIdx.x;
    if (idx < 9*3*128*32){
      int cp = idx & 31; int rest = idx >> 5;
      int oc = rest & 127; rest >>= 7;
      int cc = rest % 3; int tap = rest / 3;
      int ic = cc*32 + cp;
      float v = (ic < 96) ? w3[(oc*96 + ic)*9 + tap] : 0.f;
      wT3[idx] = __float2bfloat16(v);
    }
    return;
  }
  b -= 432;
  if (b < 1152){ // fc1 weights: [kc36][oc256][kp32], k' = rr*128 + ch (tap-major)
    int idx = b*256 + threadIdx.x;
    if (idx < 36*256*32){
      int kp = idx & 31; int oc = (idx >> 5) & 255; int kc = idx >> 13;
      int k2 = kc*32 + kp;
      int rr = k2 >> 7, ch = k2 & 127;
      wF1T[idx] = __float2bfloat16(fw1[(size_t)(ch*9 + rr)*256 + oc]);
    }
    return;
  }
  b -= 1152;
  {              // fc2 weights: [kc8][oc128][kp32]
    int idx = b*256 + threadIdx.x;
    if (idx < 8*128*32){
      int kp = idx & 31; int oc = (idx >> 5) & 127; int kc = idx >> 12;
      wF2T[idx] = __float2bfloat16(fw2[(size_t)(kc*32 + kp)*128 + oc]);
    }
  }
}

// ---------------- conv1 MFMA: 14ch fp32 NCHW -> 48ch raw bf16 padded NHWC, + stats ----------------
__launch_bounds__(256,2)
__global__ void conv1_mfma_kernel(const float* __restrict__ x, const bf16* __restrict__ wT,
                                  const float* __restrict__ bias, bf16* __restrict__ out,
                                  float* __restrict__ stats){
  constexpr int XP = 24;
  __shared__ unsigned short sX[324*XP];
  __shared__ float sStat[96];
  const int tid = threadIdx.x;
  const int lane = tid & 63, wave = tid >> 6;
  const int quad = lane >> 4, l15 = lane & 15;
  const int tileX = (blockIdx.x & 31)*16, tileY = (blockIdx.x >> 5)*16;
  if (tid < 96) sStat[tid] = 0.f;
  for (int p = tid; p < 324; p += 256){ sX[p*XP+14] = 0; sX[p*XP+15] = 0; }
  for (int idx = tid; idx < 14*324; idx += 256){
    int c = idx / 324, p = idx - c*324;
    int r = p / 18, col = p - r*18;
    int gy = tileY + r - 1, gx = tileX + col - 1;
    float v = 0.f;
    if ((unsigned)gy < 512u && (unsigned)gx < 512u) v = x[(size_t)c*NPIX + gy*512 + gx];
    sX[p*XP + c] = f2bfu(v);
  }
  __syncthreads();

  f32x4 acc[3][4];
  #pragma unroll
  for (int t = 0; t < 3; ++t){
    f32x4 bv = *(const f32x4*)(bias + t*16 + quad*4);
    #pragma unroll
    for (int s = 0; s < 4; ++s) acc[t][s] = bv;
  }
  const int pxb = wave*4;
  const int h = quad >> 1, chalf = (quad & 1)*8;
  const int T0[5] = {0,2,4,6,8};
  const int T1[5] = {1,3,5,7,8};
  #pragma unroll
  for (int kc = 0; kc < 5; ++kc){
    short8 a[3];
    #pragma unroll
    for (int t = 0; t < 3; ++t)
      a[t] = *(const short8*)((const unsigned short*)wT + (size_t)(kc*48 + t*16 + l15)*32 + quad*8);
    const int ky = h ? (T1[kc]/3) : (T0[kc]/3);
    const int kx = h ? (T1[kc]%3) : (T0[kc]%3);
    #pragma unroll
    for (int s = 0; s < 4; ++s){
      int py = pxb + s;
      short8 bfr = *(const short8*)(&sX[((py+ky)*18 + l15+kx)*XP + chalf]);
      #pragma unroll
      for (int t = 0; t < 3; ++t)
        acc[t][s] = __builtin_amdgcn_mfma_f32_16x16x32_bf16(a[t], bfr, acc[t][s], 0, 0, 0);
    }
  }
  #pragma unroll
  for (int t = 0; t < 3; ++t){
    #pragma unroll
    for (int r = 0; r < 4; ++r){
      float sv = 0.f, sq = 0.f;
      #pragma unroll
      for (int s = 0; s < 4; ++s){ float v = acc[t][s][r]; sv += v; sq += v*v; }
      #pragma unroll
      for (int m = 1; m < 16; m <<= 1){ sv += __shfl_xor(sv, m); sq += __shfl_xor(sq, m); }
      if (l15 == 0){
        atomicAdd(&sStat[(t*16 + quad*4 + r)*2],   sv);
        atomicAdd(&sStat[(t*16 + quad*4 + r)*2+1], sq);
      }
    }
    #pragma unroll
    for (int s = 0; s < 4; ++s){
      f32x4 v = acc[t][s];
      uint2 pk;
      pk.x = pack2bf(v[0], v[1]);
      pk.y = pack2bf(v[2], v[3]);
      *(uint2*)(out + ((size_t)(tileY+pxb+s+1)*PW + tileX+l15+1)*48 + t*16 + quad*4) = pk;
    }
  }
  __syncthreads();
  if (tid < 12){
    int g = tid >> 1, wsel = tid & 1;
    float v = 0.f;
    #pragma unroll
    for (int j = 0; j < 8; ++j) v += sStat[(g*8+j)*2 + wsel];
    atomicAdd(&stats[g*2 + wsel], v);
  }
}

// ---------------- in-place GN+ReLU (interior) + zero borders; 4 blocks per row ----------------
template<int C>
__global__ void norm_kernel(bf16* buf, const float* __restrict__ stats,
                            const float* __restrict__ gamma, const float* __restrict__ beta){
  __shared__ float sAB[2*C];
  const int tid = threadIdx.x;
  if (tid < C){ float A,B; computeAB(stats, gamma, beta, tid, A, B); sAB[tid]=A; sAB[C+tid]=B; }
  __syncthreads();
  const int y = blockIdx.x >> 2, q = blockIdx.x & 3;   // y 0..513
  uint4* row = (uint4*)(buf + (size_t)y*PW*C);
  constexpr int NU4 = PW*C/8/4;      // per-quarter uint4 count (divisible for C=48,96)
  const bool brow = (y == 0) | (y == 513);
  for (int i = q*NU4 + tid; i < (q+1)*NU4; i += 256){
    int e = i*8;
    int px = e / C;
    if (brow | (px == 0) | (px == 513)){ row[i] = make_uint4(0,0,0,0); continue; }
    int ch = e - px*C;
    uint4 v = row[i];
    unsigned uu[4] = {v.x,v.y,v.z,v.w}, ou[4];
    #pragma unroll
    for (int j = 0; j < 4; ++j){
      float a = fmaxf(bflo(uu[j])*sAB[ch+j*2]   + sAB[C+ch+j*2],   0.f);
      float d = fmaxf(bfhi(uu[j])*sAB[ch+j*2+1] + sAB[C+ch+j*2+1], 0.f);
      ou[j] = pack2bf(a, d);
    }
    row[i] = make_uint4(ou[0],ou[1],ou[2],ou[3]);
  }
}

// ---------------- conv2: 16x16-tile MFMA conv, R-MAJOR taps, shallow double-buffered DMA ----
// r0-verified geometry/sync (3 barriers, <=6 DMA outstanding) + the r1/r7-verified r-major
// inner loop ported from conv3: per wave, each (input-row, kx) b-frag is ds_read ONCE
// (3 kx x 10 rows = 30 reads/chunk/wave vs 72 tap-major). DMA for chunk cr+1 issues at TOP
// of chunk cr (full compute phase of latency cover vs tap==7's ~2 taps).
// Regs: a[3][3]=36 VGPR live + acc 96 -> ~248/wave, fits the 2-waves/SIMD budget.
template<int IC, int NCC, int OCT, int OC>
__launch_bounds__(256, 2)
__global__ void conv_dma16_kernel(const bf16* __restrict__ in, const bf16* __restrict__ wT,
                                  const float* __restrict__ bias,
                                  bf16* __restrict__ out, float* __restrict__ outstats){
  __shared__ unsigned short sIn[2][1296*8];   // 2 x 20736 B
  __shared__ float sStat[2*OC];
  const int tid  = threadIdx.x;
  const int lane = tid & 63, wave = tid >> 6;
  const int quad = lane >> 4, l15 = lane & 15;
  const int ocg = wave >> 1, pxg = wave & 1;
  const int tileX = (blockIdx.x & 31) * 16, tileY = (blockIdx.x >> 5) * 16;
  const int ocbase = ocg * (OCT*16);

  for (int i = tid; i < 2*OC; i += 256) sStat[i] = 0.f;

  // per-thread DMA source offsets, computed ONCE (chunk adds cr*32 elements)
  unsigned off[6];
  #pragma unroll
  for (int k = 0; k < 6; ++k){
    int slot = tid + k*256;
    if (k < 5 || tid < 16){
      int row = slot/72; int rem = slot - row*72;
      int cc = rem/18;   int col = rem - cc*18;
      // for IC=48, chunk 1 cc>=2 reads past-channel (finite) data; weights are 0 there.
      off[k] = (unsigned)(((tileY+row)*PW + tileX+col)*IC + cc*8);
    }
  }
  auto issueDMA = [&](int cr, int bi){
    #pragma unroll
    for (int k = 0; k < 6; ++k){
      if (k == 5 && tid >= 16) continue;
      dma16(in + off[k] + cr*32, &sIn[bi][(tid + k*256)*8]);
    }
  };

  f32x4 acc[OCT][8];
  #pragma unroll
  for (int t = 0; t < OCT; ++t){
    f32x4 bv = *(const f32x4*)(bias + ocbase + t*16 + quad*4);
    #pragma unroll
    for (int s = 0; s < 8; ++s) acc[t][s] = bv;
  }

  issueDMA(0, 0);
  __syncthreads();               // drains DMA(0); sStat ready

  #pragma unroll 1
  for (int cr = 0; cr < NCC; ++cr){
    if (cr + 1 < NCC) issueDMA(cr + 1, (cr + 1) & 1);   // buffer free since last barrier
    // wave-shared b base at window row pxg*8; row stride = 72 slots (4cc x 18col)
    const unsigned short* B0 = &sIn[cr & 1][(((pxg*8)*4 + quad)*18 + l15)*8];
    const unsigned short* W0 = (const unsigned short*)wT + ((size_t)cr*OC + ocbase + l15)*32 + quad*8;

    #pragma unroll
    for (int kx = 0; kx < 3; ++kx){
      short8 a[3][OCT];
      #pragma unroll
      for (int ky = 0; ky < 3; ++ky)
        #pragma unroll
        for (int t = 0; t < OCT; ++t)
          a[ky][t] = *(const short8*)(W0 + (size_t)(ky*3+kx)*(NCC*OC*32) + t*512);
      #pragma unroll
      for (int r = 0; r < 10; ++r){          // window rows pxg*8 .. pxg*8+9
        short8 b = *(const short8*)(B0 + (r*72 + kx)*8);
        #pragma unroll
        for (int ky = 0; ky < 3; ++ky){
          const int s = r - ky;
          if (s >= 0 && s < 8){
            #pragma unroll
            for (int t = 0; t < OCT; ++t)
              acc[t][s] = __builtin_amdgcn_mfma_f32_16x16x32_bf16(a[ky][t], b, acc[t][s], 0, 0, 0);
          }
        }
      }
    }
    __syncthreads();             // all waves done with this buffer; next DMA drained
  }

  // stats + store raw bf16
  #pragma unroll
  for (int t = 0; t < OCT; ++t){
    #pragma unroll
    for (int r = 0; r < 4; ++r){
      float sv = 0.f, sq = 0.f;
      #pragma unroll
      for (int s = 0; s < 8; ++s){ float v = acc[t][s][r]; sv += v; sq += v*v; }
      #pragma unroll
      for (int m = 1; m < 16; m <<= 1){ sv += __shfl_xor(sv, m); sq += __shfl_xor(sq, m); }
      if (l15 == 0){
        atomicAdd(&sStat[(ocbase + t*16 + quad*4 + r)*2],   sv);
        atomicAdd(&sStat[(ocbase + t*16 + quad*4 + r)*2+1], sq);
      }
    }
    #pragma unroll
    for (int s = 0; s < 8; ++s){
      int py = pxg*8 + s;
      f32x4 v = acc[t][s];
      uint2 pk;
      pk.x = pack2bf(v[0], v[1]);
      pk.y = pack2bf(v[2], v[3]);
      *(uint2*)(out + ((size_t)(tileY+py+1)*PW + (tileX+l15+1))*OC + ocbase + t*16 + quad*4) = pk;
    }
  }
  __syncthreads();
  if (tid < (OC/8)*2){
    int g = tid >> 1, wsel = tid & 1;
    float v = 0.f;
    #pragma unroll
    for (int j = 0; j < 8; ++j) v += sStat[(g*8+j)*2 + wsel];
    atomicAdd(&outstats[g*2 + wsel], v);
  }
}

// ---------------- conv3: 16x8-tile MFMA conv, r-major taps, shallow double buffer (r7-verified) ----
template<int IC, int NCC, int OCT, int OC, int NW, int TH>
__launch_bounds__(NW*64, 3)
__global__ void conv_dma8_kernel(const bf16* __restrict__ in, const bf16* __restrict__ wT,
                                 const float* __restrict__ bias,
                                 bf16* __restrict__ out, float* __restrict__ outstats){
  constexpr int NT   = NW*64;
  constexpr int ROWS = TH + 2;
  constexpr int SLOTS = ROWS * 72;              // 16B slots per chunk
  constexpr int K    = (SLOTS + NT - 1) / NT;
  constexpr int REM  = SLOTS - (K-1)*NT;        // active threads in last k
  __shared__ unsigned short sIn[2][SLOTS*8];    // 2 x 11520 B
  __shared__ float sStat[2*OC];
  const int tid  = threadIdx.x;
  const int lane = tid & 63, wave = tid >> 6;
  const int quad = lane >> 4, l15 = lane & 15;
  const int tileX = (blockIdx.x & 31) * 16, tileY = (blockIdx.x >> 5) * TH;
  const int ocbase = wave * (OCT*16);

  for (int i = tid; i < 2*OC; i += NT) sStat[i] = 0.f;

  // per-thread DMA source offsets, computed ONCE (chunk adds cr*32 elements)
  unsigned off[K];
  #pragma unroll
  for (int k = 0; k < K; ++k){
    int slot = tid + k*NT;
    if (k < K-1 || tid < REM){
      int row = slot/72; int rem = slot - row*72;
      int cc = rem/18;   int col = rem - cc*18;
      off[k] = (unsigned)(((tileY+row)*PW + tileX+col)*IC + cc*8);
    }
  }
  auto issueDMA = [&](int cr, int bi){
    #pragma unroll
    for (int k = 0; k < K; ++k){
      if (k == K-1 && tid >= REM) continue;
      dma16(in + off[k] + cr*32, &sIn[bi][(tid + k*NT)*8]);
    }
  };

  f32x4 acc[OCT][TH];
  #pragma unroll
  for (int t = 0; t < OCT; ++t){
    f32x4 bv = *(const f32x4*)(bias + ocbase + t*16 + quad*4);
    #pragma unroll
    for (int s = 0; s < TH; ++s) acc[t][s] = bv;
  }

  issueDMA(0, 0);
  __syncthreads();               // drains DMA(0); sStat ready

  #pragma unroll 1
  for (int cr = 0; cr < NCC; ++cr){
    if (cr + 1 < NCC) issueDMA(cr + 1, (cr + 1) & 1);   // buffer free since last barrier
    // wave-shared b base: all row/kx offsets are compile-time immediates from here
    const unsigned short* B0 = &sIn[cr & 1][(quad*18 + l15)*8];
    const unsigned short* W0 = (const unsigned short*)wT + ((size_t)cr*OC + ocbase + l15)*32 + quad*8;

    #pragma unroll
    for (int kx = 0; kx < 3; ++kx){
      short8 a[3][OCT];
      #pragma unroll
      for (int ky = 0; ky < 3; ++ky)
        #pragma unroll
        for (int t = 0; t < OCT; ++t)
          a[ky][t] = *(const short8*)(W0 + (size_t)(ky*3+kx)*(NCC*OC*32) + t*512);
      #pragma unroll
      for (int r = 0; r < ROWS; ++r){
        short8 b = *(const short8*)(B0 + (r*72 + kx)*8);
        #pragma unroll
        for (int ky = 0; ky < 3; ++ky){
          const int s = r - ky;
          if (s >= 0 && s < TH){
            #pragma unroll
            for (int t = 0; t < OCT; ++t)
              acc[t][s] = __builtin_amdgcn_mfma_f32_16x16x32_bf16(a[ky][t], b, acc[t][s], 0, 0, 0);
          }
        }
      }
    }
    __syncthreads();             // all waves done with this buffer; next DMA drained
  }

  // stats + store raw bf16
  #pragma unroll
  for (int t = 0; t < OCT; ++t){
    #pragma unroll
    for (int r = 0; r < 4; ++r){
      float sv = 0.f, sq = 0.f;
      #pragma unroll
      for (int s = 0; s < TH; ++s){ float v = acc[t][s][r]; sv += v; sq += v*v; }
      #pragma unroll
      for (int m = 1; m < 16; m <<= 1){ sv += __shfl_xor(sv, m); sq += __shfl_xor(sq, m); }
      if (l15 == 0){
        atomicAdd(&sStat[(ocbase + t*16 + quad*4 + r)*2],   sv);
        atomicAdd(&sStat[(ocbase + t*16 + quad*4 + r)*2+1], sq);
      }
    }
    #pragma unroll
    for (int s = 0; s < TH; ++s){
      f32x4 v = acc[t][s];
      uint2 pk;
      pk.x = pack2bf(v[0], v[1]);
      pk.y = pack2bf(v[2], v[3]);
      *(uint2*)(out + ((size_t)(tileY+s+1)*PW + (tileX+l15+1))*OC + ocbase + t*16 + quad*4) = pk;
    }
  }
  __syncthreads();
  if (tid < (OC/8)*2){
    int g = tid >> 1, wsel = tid & 1;
    float v = 0.f;
    #pragma unroll
    for (int j = 0; j < 8; ++j) v += sStat[(g*8+j)*2 + wsel];
    atomicAdd(&outstats[g*2 + wsel], v);
  }
}

// ---------------- MEGA: gather+GN+ReLU -> FC1(MFMA) -> FC2(MFMA) -> heads ->
//                  log_prob/entropy/scatter, plus 1 pool row per block. 512 blocks x 16 cells. ----
__launch_bounds__(256)
__global__ void mega_kernel(const bf16* __restrict__ f, const float* __restrict__ instats,
                            const float* __restrict__ gamma, const float* __restrict__ beta,
                            const int* __restrict__ cell_i, const int* __restrict__ cell_j,
                            const int* __restrict__ action,
                            const bf16* __restrict__ wT, const float* __restrict__ fb1,
                            const bf16* __restrict__ wT2, const float* __restrict__ fb2,
                            const float* __restrict__ bw, const float* __restrict__ bb,
                            const float* __restrict__ iw, const float* __restrict__ ib,
                            const float* __restrict__ tw, const float* __restrict__ tb,
                            float* __restrict__ pooled, float* __restrict__ out){
  constexpr int KST = 1160;               // fc1 k stride (shorts)
  __shared__ unsigned short sG[16*KST];   // 37120 B; overlaid by h2L after FC1 reads done
  __shared__ unsigned short h1L[16*264];  // 8448 B
  __shared__ float sAB[256];
  __shared__ int sij[32];
  __shared__ float sRed[2];
  __shared__ float sP[128];
  float* h2L = (float*)sG;                // 16*132 fp32 = 8448 B (inside sG)
  const int tid = threadIdx.x;
  const int lane = tid & 63, wave = tid >> 6;
  const int quad = lane >> 4, l15 = lane & 15;
  const int cb = blockIdx.x*16;

  if (tid < 2) sRed[tid] = 0.f;
  if (tid < 128){ float A,B; computeAB(instats, gamma, beta, tid, A, B);
    sAB[tid]=A; sAB[128+tid]=B; sP[tid]=0.f; }
  if (tid < 16) sij[tid] = cell_i[cb + tid];
  else if (tid < 32) sij[tid] = cell_j[cb + tid - 16];
  __syncthreads();

  // phase 1: gather 16 cells' 3x3x128 patches (GN+ReLU) -> sG [cell][k'=rr*128+ch]
  for (int idx = tid; idx < 16*144; idx += 256){
    int c8 = idx & 15; int t2 = idx >> 4;
    int cell = t2 / 9, rr = t2 - cell*9;
    int r = rr/3, cl = rr - r*3;
    int py = sij[cell] + r, px = sij[16+cell] + cl;   // padded coords
    uint4 v = *(const uint4*)(f + ((size_t)py*PW + px)*128 + c8*8);
    bool border = (py==0) | (py==513) | (px==0) | (px==513);
    unsigned uu[4] = {v.x, v.y, v.z, v.w};
    unsigned ou[4];
    #pragma unroll
    for (int j = 0; j < 4; ++j){
      int ch = c8*8 + j*2;
      float a = border ? 0.f : fmaxf(bflo(uu[j])*sAB[ch]   + sAB[128+ch],   0.f);
      float d = border ? 0.f : fmaxf(bfhi(uu[j])*sAB[ch+1] + sAB[128+ch+1], 0.f);
      ou[j] = pack2bf(a, d);
    }
    uint4 wv; wv.x = ou[0]; wv.y = ou[1]; wv.z = ou[2]; wv.w = ou[3];
    *(uint4*)(&sG[cell*KST + rr*128 + c8*8]) = wv;
  }
  __syncthreads();

  // phase 2: FC1 MFMA (1152 -> 256), wave owns oc [wave*64, wave*64+64)
  {
    f32x4 acc[4];
    const int ocb = wave*64;
    #pragma unroll
    for (int t = 0; t < 4; ++t)
      acc[t] = *(const f32x4*)(fb1 + ocb + t*16 + quad*4);
    #pragma unroll 2
    for (int kc = 0; kc < 36; ++kc){
      short8 b = *(const short8*)(&sG[l15*KST + kc*32 + quad*8]);
      #pragma unroll
      for (int t = 0; t < 4; ++t){
        short8 a = *(const short8*)((const unsigned short*)wT + ((size_t)kc*256 + ocb + t*16 + l15)*32 + quad*8);
        acc[t] = __builtin_amdgcn_mfma_f32_16x16x32_bf16(a, b, acc[t], 0, 0, 0);
      }
    }
    // phase 3: relu -> bf16 -> h1L [cell][oc] stride 264
    #pragma unroll
    for (int t = 0; t < 4; ++t){
      f32x4 v = acc[t];
      uint2 pk;
      pk.x = pack2bf(fmaxf(v[0],0.f), fmaxf(v[1],0.f));
      pk.y = pack2bf(fmaxf(v[2],0.f), fmaxf(v[3],0.f));
      *(uint2*)(&h1L[l15*264 + ocb + t*16 + quad*4]) = pk;
    }
  }
  __syncthreads();

  // phase 4: FC2 MFMA (256 -> 128); wave owns oc [wave*32, wave*32+32)
  {
    const int och = wave*32;
    f32x4 acc2[2];
    #pragma unroll
    for (int t = 0; t < 2; ++t)
      acc2[t] = *(const f32x4*)(fb2 + och + t*16 + quad*4);
    #pragma unroll
    for (int kc = 0; kc < 8; ++kc){
      short8 b = *(const short8*)(&h1L[l15*264 + kc*32 + quad*8]);
      #pragma unroll
      for (int t = 0; t < 2; ++t){
        short8 a = *(const short8*)((const unsigned short*)wT2 + ((size_t)kc*128 + och + t*16 + l15)*32 + quad*8);
        acc2[t] = __builtin_amdgcn_mfma_f32_16x16x32_bf16(a, b, acc2[t], 0, 0, 0);
      }
    }
    // phase 5: relu -> h2L fp32 [cell][oc] stride 132 (overlays sG; sG dead since phase-3 barrier)
    #pragma unroll
    for (int t = 0; t < 2; ++t){
      f32x4 v = acc2[t];
      #pragma unroll
      for (int r = 0; r < 4; ++r) v[r] = fmaxf(v[r], 0.f);
      *(f32x4*)(&h2L[l15*132 + och + t*16 + quad*4]) = v;
    }
  }
  __syncthreads();

  // phase 6: heads (16 cells x 12 outs) + log_prob/entropy/scatter
  if (tid < 192){
    int cell = tid/12, jj = tid - cell*12;
    int which = jj >> 2, o = jj & 3;
    const float* W  = (which==0) ? bw : (which==1 ? iw : tw);
    const float* Bp = (which==0) ? bb : (which==1 ? ib : tb);
    float d = Bp[o];
    const float* h2 = &h2L[cell*132];
    for (int k = 0; k < 128; k++) d += h2[k]*W[k*4+o];
    int cellg = cb + cell;
    if (which == 1){
      out[262147 + cellg*4 + o] = d;
    } else if (which == 2){
      out[262147 + 32768 + cellg*4 + o] = d;
    } else {
      float p = 1.f/(1.f + __expf(-d));
      p = fminf(fmaxf(p, 1e-7f), 1.f - 1e-7f);
      int a = action[cellg*4 + o];
      float lp  = a ? __logf(p) : __logf(1.f-p);
      float ent = -(p*__logf(p) + (1.f-p)*__logf(1.f-p));
      atomicAdd(&sRed[0], lp);
      atomicAdd(&sRed[1], ent);
      if (a){
        const int di[4] = {-1,0,1,0};
        const int dj[4] = {0,1,0,-1};
        int ni = sij[cell] + di[o];
        int nj = sij[16+cell] + dj[o];
        if ((unsigned)ni < 512u && (unsigned)nj < 512u)
          out[ni*512 + nj] = 1.0f;
      }
    }
  }

  // phase 7: global-avg-pool, 1 row per block (512 blocks <-> 512 rows)
  {
    const int gl = tid & 15, xl = tid >> 4;
    float A[8], B[8];
    #pragma unroll
    for (int j = 0; j < 8; ++j){ A[j] = sAB[gl*8+j]; B[j] = sAB[128+gl*8+j]; }
    const int y = blockIdx.x;     // 0..511
    float ps[8] = {0,0,0,0,0,0,0,0};
    for (int x2 = xl; x2 < 512; x2 += 16){
      uint4 v = *(const uint4*)(f + ((size_t)(y+1)*PW + x2+1)*128 + gl*8);
      unsigned uu[4] = {v.x, v.y, v.z, v.w};
      #pragma unroll
      for (int j = 0; j < 4; ++j){
        ps[j*2]   += fmaxf(bflo(uu[j])*A[j*2]   + B[j*2],   0.f);
        ps[j*2+1] += fmaxf(bfhi(uu[j])*A[j*2+1] + B[j*2+1], 0.f);
      }
    }
    #pragma unroll
    for (int j = 0; j < 8; ++j) atomicAdd(&sP[gl*8+j], ps[j]);
  }
  __syncthreads();
  if (tid == 0){
    atomicAdd(&out[262144], sRed[0]);
    atomicAdd(&out[262145], sRed[1]);
  }
  if (tid < 128) atomicAdd(&pooled[tid], sP[tid]);
}

// ---------------- value head MLP ----------------
__global__ void value_kernel(const float* __restrict__ pooled, const float* __restrict__ vw1,
                             const float* __restrict__ vb1, const float* __restrict__ vw2,
                             const float* __restrict__ vb2, float* __restrict__ out){
  int t = threadIdx.x;   // 64 threads
  float h = vb1[t];
  const float invN = 1.f/262144.f;
  for (int c = 0; c < 128; c++) h += (pooled[c]*invN)*vw1[c*64+t];
  h = fmaxf(h, 0.f);
  float v = h*vw2[t];
  #pragma unroll
  for (int off = 32; off; off >>= 1) v += __shfl_xor(v, off);
  if (t == 0) out[262146] = v + vb2[0];
}

extern "C" void kernel_launch(void* const* d_in, const int* in_sizes, int n_in,
                              void* d_out, int out_size, void* d_ws, size_t ws_size,
                              hipStream_t stream) {
  (void)in_sizes; (void)n_in; (void)out_size; (void)ws_size;
  const float* x      = (const float*)d_in[0];
  const int*  cell_i  = (const int*)d_in[1];
  const int*  cell_j  = (const int*)d_in[2];
  const int*  action  = (const int*)d_in[3];
  const float* w1 = (const float*)d_in[4];  const float* b1 = (const float*)d_in[5];
  const float* g1 = (const float*)d_in[6];  const float* be1= (const float*)d_in[7];
  const float* w2 = (const float*)d_in[8];  const float* b2 = (const float*)d_in[9];
  const float* g2 = (const float*)d_in[10]; const float* be2= (const float*)d_in[11];
  const float* w3 = (const float*)d_in[12]; const float* b3 = (const float*)d_in[13];
  const float* g3 = (const float*)d_in[14]; const float* be3= (const float*)d_in[15];
  const float* fw1= (const float*)d_in[16]; const float* fb1= (const float*)d_in[17];
  const float* fw2= (const float*)d_in[18]; const float* fb2= (const float*)d_in[19];
  const float* bw = (const float*)d_in[20]; const float* bb = (const float*)d_in[21];
  const float* iw = (const float*)d_in[22]; const float* ib = (const float*)d_in[23];
  const float* tw = (const float*)d_in[24]; const float* tb = (const float*)d_in[25];
  const float* vw1= (const float*)d_in[26]; const float* vb1= (const float*)d_in[27];
  const float* vw2= (const float*)d_in[28]; const float* vb2= (const float*)d_in[29];

  float* out = (float*)d_out;
  char* ws = (char*)d_ws;
  bf16* buf1 = (bf16*)(ws);                       // 25,362,816 (+small overread slack into buf2)
  bf16* buf2 = (bf16*)(ws + 25362816);            // -> 76,088,448
  bf16* bufF = (bf16*)(ws + 76088448);            // -> 143,722,624
  bf16* wT2  = (bf16*)(ws + 143722624);           // 110,592  -> 143,833,216
  bf16* wT3  = (bf16*)(ws + 143833216);           // 221,184  -> 144,054,400
  bf16* wT1  = (bf16*)(ws + 144054400);           // 15,360   -> 144,069,760
  bf16* wF1T = (bf16*)(ws + 144069760);           // 589,824  -> 144,659,584
  bf16* wF2T = (bf16*)(ws + 144659584);           // 65,536   -> 144,725,120
  float* statsf = (float*)(ws + 144725120);       // 68 floats (L1:0, L2:12, L3:36)
  float* pooled = statsf + 128;                   // 128 floats

  setup_kernel<<<2983, 256, 0, stream>>>(out, statsf, pooled, w1, wT1, w2, wT2, w3, wT3,
                                         fw1, wF1T, fw2, wF2T);
  conv1_mfma_kernel<<<1024, 256, 0, stream>>>(x, wT1, b1, buf1, statsf + 0);
  norm_kernel<48><<<514*4, 256, 0, stream>>>(buf1, statsf + 0, g1, be1);
  // conv2: 16x16 tile + r-major taps (30 ds_reads/chunk/wave vs 72), grid 32x32
  conv_dma16_kernel<48,2,3,96><<<1024, 256, 0, stream>>>(buf1, wT2, b2, buf2, statsf + 12);
  norm_kernel<96><<<514*4, 256, 0, stream>>>(buf2, statsf + 12, g2, be2);
  // conv3: r7-verified 16x8 tile, TH=8, 3 waves/SIMD, grid 32x64
  conv_dma8_kernel<96,3,2,128,4,8><<<2048, 256, 0, stream>>>(buf2, wT3, b3, bufF, statsf + 36);
  mega_kernel<<<512, 256, 0, stream>>>(bufF, statsf + 36, g3, be3, cell_i, cell_j, action,
                                       wF1T, fb1, wF2T, fb2, bw, bb, iw, ib, tw, tb,
                                       pooled, out);
  value_kernel<<<1, 64, 0, stream>>>(pooled, vw1, vb1, vw2, vb2, out);
}

// Round 12
// 347.653 us; speedup vs baseline: 1.1454x; 1.0246x over previous
//
#include <hip/hip_runtime.h>
#include <hip/hip_bf16.h>
#include <cstddef>

#define NPIX 262144   // 512*512
#define PW 514        // padded width/height
typedef __hip_bfloat16 bf16;
typedef __attribute__((ext_vector_type(8))) short short8;
typedef __attribute__((ext_vector_type(4))) float f32x4;

__device__ inline unsigned short f2bfu(float f){
  __hip_bfloat16 h = __float2bfloat16(f);
  return *(reinterpret_cast<unsigned short*>(&h));
}
__device__ inline float bflo(unsigned u){ return __uint_as_float(u<<16); }
__device__ inline float bfhi(unsigned u){ return __uint_as_float(u & 0xffff0000u); }
// cheap pair pack: round-half-up bf16, low16=a, high16=b (values finite here)
__device__ inline unsigned pack2bf(float a, float b){
  unsigned ua = __float_as_uint(a), ub = __float_as_uint(b);
  return ((ua + 0x8000u) >> 16) | ((ub + 0x8000u) & 0xffff0000u);
}
// async global->LDS 16B DMA (wave-uniform LDS base + lane*16; gptr per-lane)
// HAZARD ENVELOPE (r5/r6 vs r0/r7/r11): <=6 LDS-DMA outstanding per wave at a vmcnt(0)
// drain is VERIFIED SAFE (conv2's pattern, absmax-clean 3 sessions); 9 outstanding
// CORRUPTED sporadically (absmax 0.0078 -> 128). Never exceed 6 at any drain.
// FUSION NOTE (r3/r4/r8): GN+ReLU fusion into conv staging retired (3 attempts, all slow).
// OCCUPANCY NOTE (r9): TH=4 raised occupancy 27->37% but SLOWED conv3 (+20%): limiter is
// per-block barrier/drain critical path, not wave count. TH=8 / 3 waves/SIMD is optimal.
// R-MAJOR NOTE (r11): r-major taps at OCT=3 (conv2) was NEUTRAL-NEGATIVE (36 VGPR a-frags
// on top of 96 AGPR acc at 2 waves/SIMD); keep conv2 tap-major, conv3 (OCT=2) r-major.
__device__ inline void dma16(const bf16* g, unsigned short* l){
  __builtin_amdgcn_global_load_lds(
      (const __attribute__((address_space(1))) unsigned int*)g,
      (__attribute__((address_space(3))) unsigned int*)l, 16, 0, 0);
}

// group-norm affine from accumulated stats (8 channels per group, 262144 px)
__device__ inline void computeAB(const float* stats, const float* gamma, const float* beta,
                                 int c, float& A, float& B){
  int g = c >> 3;
  const float invN = 1.f/2097152.f;
  float m = stats[g*2]*invN;
  float v = stats[g*2+1]*invN - m*m;
  float inv = rsqrtf(v + 1e-5f);
  A = inv*gamma[c];
  B = beta[c] - m*A;
}

// ---------------- merged setup: zero init + all 5 weight transforms ----------------
__global__ void setup_kernel(float* out, float* stats, float* pooled,
                             const float* __restrict__ w1, bf16* __restrict__ wT1,
                             const float* __restrict__ w2, bf16* __restrict__ wT2,
                             const float* __restrict__ w3, bf16* __restrict__ wT3,
                             const float* __restrict__ fw1, bf16* __restrict__ wF1T,
                             const float* __restrict__ fw2, bf16* __restrict__ wF2T){
  int b = blockIdx.x;
  if (b < 1025){
    int i = b*256 + threadIdx.x;
    if (i < 262147) out[i] = 0.f;            // grid + log_prob + entropy + value
    if (i < 68)  stats[i]  = 0.f;
    if (i < 128) pooled[i] = 0.f;
    return;
  }
  b -= 1025;
  if (b < 30){   // conv1 weights: [kc5][oc48][kp32], k = tap*16 + c
    int idx = b*256 + threadIdx.x;
    if (idx < 5*48*32){
      int kp = idx & 31; int oc = (idx >> 5) % 48; int kc = idx / (48*32);
      int k = kc*32 + kp;
      int tap = k >> 4, c = k & 15;
      float v = (tap < 9 && c < 14) ? w1[(oc*14 + c)*9 + tap] : 0.f;
      wT1[idx] = __float2bfloat16(v);
    }
    return;
  }
  b -= 30;
  if (b < 216){  // conv2 weights: [tap][cc2][oc96][cp32] (ic 48..63 zero!)
    int idx = b*256 + threadIdx.x;
    if (idx < 9*2*96*32){
      int cp = idx & 31; int rest = idx >> 5;
      int oc = rest % 96; rest /= 96;
      int cc = rest % 2; int tap = rest / 2;
      int ic = cc*32 + cp;
      float v = (ic < 48) ? w2[(oc*48 + ic)*9 + tap] : 0.f;
      wT2[idx] = __float2bfloat16(v);
    }
    return;
  }
  b -= 216;
  if (b < 432){  // conv3 weights: [tap][cc3][oc128][cp32]
    int idx = b*256 + threadIdx.x;
    if (idx < 9*3*128*32){
      int cp = idx & 31; int rest = idx >> 5;
      int oc = rest & 127; rest >>= 7;
      int cc = rest % 3; int tap = rest / 3;
      int ic = cc*32 + cp;
      float v = (ic < 96) ? w3[(oc*96 + ic)*9 + tap] : 0.f;
      wT3[idx] = __float2bfloat16(v);
    }
    return;
  }
  b -= 432;
  if (b < 1152){ // fc1 weights: [kc36][oc256][kp32], k' = rr*128 + ch (tap-major)
    int idx = b*256 + threadIdx.x;
    if (idx < 36*256*32){
      int kp = idx & 31; int oc = (idx >> 5) & 255; int kc = idx >> 13;
      int k2 = kc*32 + kp;
      int rr = k2 >> 7, ch = k2 & 127;
      wF1T[idx] = __float2bfloat16(fw1[(size_t)(ch*9 + rr)*256 + oc]);
    }
    return;
  }
  b -= 1152;
  {              // fc2 weights: [kc8][oc128][kp32]
    int idx = b*256 + threadIdx.x;
    if (idx < 8*128*32){
      int kp = idx & 31; int oc = (idx >> 5) & 127; int kc = idx >> 12;
      wF2T[idx] = __float2bfloat16(fw2[(size_t)(kc*32 + kp)*128 + oc]);
    }
  }
}

// ---------------- conv1 MFMA: 14ch fp32 NCHW -> 48ch raw bf16 padded NHWC, + stats ----------------
__launch_bounds__(256,2)
__global__ void conv1_mfma_kernel(const float* __restrict__ x, const bf16* __restrict__ wT,
                                  const float* __restrict__ bias, bf16* __restrict__ out,
                                  float* __restrict__ stats){
  constexpr int XP = 24;
  __shared__ unsigned short sX[324*XP];
  __shared__ float sStat[96];
  const int tid = threadIdx.x;
  const int lane = tid & 63, wave = tid >> 6;
  const int quad = lane >> 4, l15 = lane & 15;
  const int tileX = (blockIdx.x & 31)*16, tileY = (blockIdx.x >> 5)*16;
  if (tid < 96) sStat[tid] = 0.f;
  for (int p = tid; p < 324; p += 256){ sX[p*XP+14] = 0; sX[p*XP+15] = 0; }
  for (int idx = tid; idx < 14*324; idx += 256){
    int c = idx / 324, p = idx - c*324;
    int r = p / 18, col = p - r*18;
    int gy = tileY + r - 1, gx = tileX + col - 1;
    float v = 0.f;
    if ((unsigned)gy < 512u && (unsigned)gx < 512u) v = x[(size_t)c*NPIX + gy*512 + gx];
    sX[p*XP + c] = f2bfu(v);
  }
  __syncthreads();

  f32x4 acc[3][4];
  #pragma unroll
  for (int t = 0; t < 3; ++t){
    f32x4 bv = *(const f32x4*)(bias + t*16 + quad*4);
    #pragma unroll
    for (int s = 0; s < 4; ++s) acc[t][s] = bv;
  }
  const int pxb = wave*4;
  const int h = quad >> 1, chalf = (quad & 1)*8;
  const int T0[5] = {0,2,4,6,8};
  const int T1[5] = {1,3,5,7,8};
  #pragma unroll
  for (int kc = 0; kc < 5; ++kc){
    short8 a[3];
    #pragma unroll
    for (int t = 0; t < 3; ++t)
      a[t] = *(const short8*)((const unsigned short*)wT + (size_t)(kc*48 + t*16 + l15)*32 + quad*8);
    const int ky = h ? (T1[kc]/3) : (T0[kc]/3);
    const int kx = h ? (T1[kc]%3) : (T0[kc]%3);
    #pragma unroll
    for (int s = 0; s < 4; ++s){
      int py = pxb + s;
      short8 bfr = *(const short8*)(&sX[((py+ky)*18 + l15+kx)*XP + chalf]);
      #pragma unroll
      for (int t = 0; t < 3; ++t)
        acc[t][s] = __builtin_amdgcn_mfma_f32_16x16x32_bf16(a[t], bfr, acc[t][s], 0, 0, 0);
    }
  }
  #pragma unroll
  for (int t = 0; t < 3; ++t){
    #pragma unroll
    for (int r = 0; r < 4; ++r){
      float sv = 0.f, sq = 0.f;
      #pragma unroll
      for (int s = 0; s < 4; ++s){ float v = acc[t][s][r]; sv += v; sq += v*v; }
      #pragma unroll
      for (int m = 1; m < 16; m <<= 1){ sv += __shfl_xor(sv, m); sq += __shfl_xor(sq, m); }
      if (l15 == 0){
        atomicAdd(&sStat[(t*16 + quad*4 + r)*2],   sv);
        atomicAdd(&sStat[(t*16 + quad*4 + r)*2+1], sq);
      }
    }
    #pragma unroll
    for (int s = 0; s < 4; ++s){
      f32x4 v = acc[t][s];
      uint2 pk;
      pk.x = pack2bf(v[0], v[1]);
      pk.y = pack2bf(v[2], v[3]);
      *(uint2*)(out + ((size_t)(tileY+pxb+s+1)*PW + tileX+l15+1)*48 + t*16 + quad*4) = pk;
    }
  }
  __syncthreads();
  if (tid < 12){
    int g = tid >> 1, wsel = tid & 1;
    float v = 0.f;
    #pragma unroll
    for (int j = 0; j < 8; ++j) v += sStat[(g*8+j)*2 + wsel];
    atomicAdd(&stats[g*2 + wsel], v);
  }
}

// ---------------- in-place GN+ReLU (interior) + zero borders; 4 blocks per row ----------------
template<int C>
__global__ void norm_kernel(bf16* buf, const float* __restrict__ stats,
                            const float* __restrict__ gamma, const float* __restrict__ beta){
  __shared__ float sAB[2*C];
  const int tid = threadIdx.x;
  if (tid < C){ float A,B; computeAB(stats, gamma, beta, tid, A, B); sAB[tid]=A; sAB[C+tid]=B; }
  __syncthreads();
  const int y = blockIdx.x >> 2, q = blockIdx.x & 3;   // y 0..513
  uint4* row = (uint4*)(buf + (size_t)y*PW*C);
  constexpr int NU4 = PW*C/8/4;      // per-quarter uint4 count (divisible for C=48,96)
  const bool brow = (y == 0) | (y == 513);
  for (int i = q*NU4 + tid; i < (q+1)*NU4; i += 256){
    int e = i*8;
    int px = e / C;
    if (brow | (px == 0) | (px == 513)){ row[i] = make_uint4(0,0,0,0); continue; }
    int ch = e - px*C;
    uint4 v = row[i];
    unsigned uu[4] = {v.x,v.y,v.z,v.w}, ou[4];
    #pragma unroll
    for (int j = 0; j < 4; ++j){
      float a = fmaxf(bflo(uu[j])*sAB[ch+j*2]   + sAB[C+ch+j*2],   0.f);
      float d = fmaxf(bfhi(uu[j])*sAB[ch+j*2+1] + sAB[C+ch+j*2+1], 0.f);
      ou[j] = pack2bf(a, d);
    }
    row[i] = make_uint4(ou[0],ou[1],ou[2],ou[3]);
  }
}

// ---------------- conv2: 16x16-tile MFMA conv, tap-major, shallow double-buffered DMA ----
// r0/r7/r11-verified. LDS slot (row,cc,col) = (row*4+cc)*18 + col (16B each).
template<int IC, int NCC, int OCT, int OC>
__launch_bounds__(256, 2)
__global__ void conv_dma16_kernel(const bf16* __restrict__ in, const bf16* __restrict__ wT,
                                  const float* __restrict__ bias,
                                  bf16* __restrict__ out, float* __restrict__ outstats){
  __shared__ unsigned short sIn[2][1296*8];   // 2 x 20736 B
  __shared__ float sStat[2*OC];
  const int tid  = threadIdx.x;
  const int lane = tid & 63, wave = tid >> 6;
  const int quad = lane >> 4, l15 = lane & 15;
  const int ocg = wave >> 1, pxg = wave & 1;
  const int tileX = (blockIdx.x & 31) * 16, tileY = (blockIdx.x >> 5) * 16;
  const int ocbase = ocg * (OCT*16);

  for (int i = tid; i < 2*OC; i += 256) sStat[i] = 0.f;

  // per-thread DMA source offsets, computed ONCE (chunk adds cr*32 elements)
  unsigned off[6];
  #pragma unroll
  for (int k = 0; k < 6; ++k){
    int slot = tid + k*256;
    if (k < 5 || tid < 16){
      int row = slot/72; int rem = slot - row*72;
      int cc = rem/18;   int col = rem - cc*18;
      // for IC=48, chunk 1 cc>=2 reads past-channel (finite) data; weights are 0 there.
      off[k] = (unsigned)(((tileY+row)*PW + tileX+col)*IC + cc*8);
    }
  }
  auto issueDMA = [&](int cr, int bi){
    #pragma unroll
    for (int k = 0; k < 6; ++k){
      if (k == 5 && tid >= 16) continue;
      dma16(in + off[k] + cr*32, &sIn[bi][(tid + k*256)*8]);
    }
  };

  f32x4 acc[OCT][8];
  #pragma unroll
  for (int t = 0; t < OCT; ++t){
    f32x4 bv = *(const f32x4*)(bias + ocbase + t*16 + quad*4);
    #pragma unroll
    for (int s = 0; s < 8; ++s) acc[t][s] = bv;
  }

  issueDMA(0, 0);
  __syncthreads();               // drains DMA(0); sStat ready

  #pragma unroll 1
  for (int cr = 0; cr < NCC; ++cr){
    // wave-shared b base: all tap/s offsets are compile-time immediates from here
    const unsigned short* B0 = &sIn[cr & 1][(((pxg*8)*4 + quad)*18 + l15)*8];
    const unsigned short* W0 = (const unsigned short*)wT + ((size_t)cr*OC + ocbase + l15)*32 + quad*8;

    #pragma unroll
    for (int tap = 0; tap < 9; ++tap){
      if (tap == 7 && cr + 1 < NCC) issueDMA(cr + 1, (cr + 1) & 1);
      const int ky = tap/3, kx = tap - ky*3;
      short8 a[OCT];
      #pragma unroll
      for (int t = 0; t < OCT; ++t)
        a[t] = *(const short8*)(W0 + (size_t)tap*(NCC*OC*32) + t*512);
      #pragma unroll
      for (int s = 0; s < 8; ++s){
        short8 b = *(const short8*)(B0 + ((s+ky)*72 + kx)*8);
        #pragma unroll
        for (int t = 0; t < OCT; ++t)
          acc[t][s] = __builtin_amdgcn_mfma_f32_16x16x32_bf16(a[t], b, acc[t][s], 0, 0, 0);
      }
    }
    __syncthreads();             // all waves done with this buffer; next DMA drained
  }

  // stats + store raw bf16
  #pragma unroll
  for (int t = 0; t < OCT; ++t){
    #pragma unroll
    for (int r = 0; r < 4; ++r){
      float sv = 0.f, sq = 0.f;
      #pragma unroll
      for (int s = 0; s < 8; ++s){ float v = acc[t][s][r]; sv += v; sq += v*v; }
      #pragma unroll
      for (int m = 1; m < 16; m <<= 1){ sv += __shfl_xor(sv, m); sq += __shfl_xor(sq, m); }
      if (l15 == 0){
        atomicAdd(&sStat[(ocbase + t*16 + quad*4 + r)*2],   sv);
        atomicAdd(&sStat[(ocbase + t*16 + quad*4 + r)*2+1], sq);
      }
    }
    #pragma unroll
    for (int s = 0; s < 8; ++s){
      int py = pxg*8 + s;
      f32x4 v = acc[t][s];
      uint2 pk;
      pk.x = pack2bf(v[0], v[1]);
      pk.y = pack2bf(v[2], v[3]);
      *(uint2*)(out + ((size_t)(tileY+py+1)*PW + (tileX+l15+1))*OC + ocbase + t*16 + quad*4) = pk;
    }
  }
  __syncthreads();
  if (tid < (OC/8)*2){
    int g = tid >> 1, wsel = tid & 1;
    float v = 0.f;
    #pragma unroll
    for (int j = 0; j < 8; ++j) v += sStat[(g*8+j)*2 + wsel];
    atomicAdd(&outstats[g*2 + wsel], v);
  }
}

// ---------------- conv3: 16x8-tile MFMA conv, r-major taps, TRI-BUFFER two-phase staging ----
// r7-verified compute loop. NEW schedule: chunks 0+1 staged up front (6 DMA/thread -- the
// VERIFIED-SAFE drain count, == conv2's pattern), one barrier, chunk 2 staged (3/thread)
// with TWO compute phases of cover, one barrier, chunk 2 computed. Barriers 4 -> 3; the
// two marginally-covered mid-loop drains become one fully-covered drain. Buffers are
// per-chunk (never rewritten -> no WAR). Max outstanding at any drain: 6 (r5/r6's unsafe
// case was 9 -- do not raise).
template<int IC, int NCC, int OCT, int OC, int NW, int TH>
__launch_bounds__(NW*64, 3)
__global__ void conv_dma8_kernel(const bf16* __restrict__ in, const bf16* __restrict__ wT,
                                 const float* __restrict__ bias,
                                 bf16* __restrict__ out, float* __restrict__ outstats){
  constexpr int NT   = NW*64;
  constexpr int ROWS = TH + 2;
  constexpr int SLOTS = ROWS * 72;              // 16B slots per chunk
  constexpr int K    = (SLOTS + NT - 1) / NT;
  constexpr int REM  = SLOTS - (K-1)*NT;        // active threads in last k
  static_assert(NCC == 3, "conv3 path");
  static_assert(2*K <= 6, "drain depth must stay within verified-safe envelope");
  __shared__ unsigned short sIn[NCC][SLOTS*8];  // 3 x 11520 B, one buffer per chunk
  __shared__ float sStat[2*OC];
  const int tid  = threadIdx.x;
  const int lane = tid & 63, wave = tid >> 6;
  const int quad = lane >> 4, l15 = lane & 15;
  const int tileX = (blockIdx.x & 31) * 16, tileY = (blockIdx.x >> 5) * TH;
  const int ocbase = wave * (OCT*16);

  for (int i = tid; i < 2*OC; i += NT) sStat[i] = 0.f;

  // per-thread DMA source offsets, computed ONCE (chunk adds cr*32 elements)
  unsigned off[K];
  #pragma unroll
  for (int k = 0; k < K; ++k){
    int slot = tid + k*NT;
    if (k < K-1 || tid < REM){
      int row = slot/72; int rem = slot - row*72;
      int cc = rem/18;   int col = rem - cc*18;
      off[k] = (unsigned)(((tileY+row)*PW + tileX+col)*IC + cc*8);
    }
  }
  auto issueDMA = [&](int cr){
    #pragma unroll
    for (int k = 0; k < K; ++k){
      if (k == K-1 && tid >= REM) continue;
      dma16(in + off[k] + cr*32, &sIn[cr][(tid + k*NT)*8]);
    }
  };

  f32x4 acc[OCT][TH];
  #pragma unroll
  for (int t = 0; t < OCT; ++t){
    f32x4 bv = *(const f32x4*)(bias + ocbase + t*16 + quad*4);
    #pragma unroll
    for (int s = 0; s < TH; ++s) acc[t][s] = bv;
  }

  auto computeChunk = [&](int cr){
    // wave-shared b base: all row/kx offsets are compile-time immediates from here
    const unsigned short* B0 = &sIn[cr][(quad*18 + l15)*8];
    const unsigned short* W0 = (const unsigned short*)wT + ((size_t)cr*OC + ocbase + l15)*32 + quad*8;
    #pragma unroll
    for (int kx = 0; kx < 3; ++kx){
      short8 a[3][OCT];
      #pragma unroll
      for (int ky = 0; ky < 3; ++ky)
        #pragma unroll
        for (int t = 0; t < OCT; ++t)
          a[ky][t] = *(const short8*)(W0 + (size_t)(ky*3+kx)*(NCC*OC*32) + t*512);
      #pragma unroll
      for (int r = 0; r < ROWS; ++r){
        short8 b = *(const short8*)(B0 + (r*72 + kx)*8);
        #pragma unroll
        for (int ky = 0; ky < 3; ++ky){
          const int s = r - ky;
          if (s >= 0 && s < TH){
            #pragma unroll
            for (int t = 0; t < OCT; ++t)
              acc[t][s] = __builtin_amdgcn_mfma_f32_16x16x32_bf16(a[ky][t], b, acc[t][s], 0, 0, 0);
          }
        }
      }
    }
  };

  // ---- two-phase staging: max 6 outstanding at drain 1 (verified-safe), 3 at drain 2 ----
  issueDMA(0);
  issueDMA(1);                   // 2*K = 6 per thread
  __syncthreads();               // drains chunks 0+1; sStat published
  issueDMA(2);                   // K = 3 per thread; 2 compute phases of cover below
  computeChunk(0);
  computeChunk(1);
  __syncthreads();               // drains chunk 2 (fully covered)
  computeChunk(2);

  // stats + store raw bf16
  #pragma unroll
  for (int t = 0; t < OCT; ++t){
    #pragma unroll
    for (int r = 0; r < 4; ++r){
      float sv = 0.f, sq = 0.f;
      #pragma unroll
      for (int s = 0; s < TH; ++s){ float v = acc[t][s][r]; sv += v; sq += v*v; }
      #pragma unroll
      for (int m = 1; m < 16; m <<= 1){ sv += __shfl_xor(sv, m); sq += __shfl_xor(sq, m); }
      if (l15 == 0){
        atomicAdd(&sStat[(ocbase + t*16 + quad*4 + r)*2],   sv);
        atomicAdd(&sStat[(ocbase + t*16 + quad*4 + r)*2+1], sq);
      }
    }
    #pragma unroll
    for (int s = 0; s < TH; ++s){
      f32x4 v = acc[t][s];
      uint2 pk;
      pk.x = pack2bf(v[0], v[1]);
      pk.y = pack2bf(v[2], v[3]);
      *(uint2*)(out + ((size_t)(tileY+s+1)*PW + (tileX+l15+1))*OC + ocbase + t*16 + quad*4) = pk;
    }
  }
  __syncthreads();
  if (tid < (OC/8)*2){
    int g = tid >> 1, wsel = tid & 1;
    float v = 0.f;
    #pragma unroll
    for (int j = 0; j < 8; ++j) v += sStat[(g*8+j)*2 + wsel];
    atomicAdd(&outstats[g*2 + wsel], v);
  }
}

// ---------------- MEGA: gather+GN+ReLU -> FC1(MFMA) -> FC2(MFMA) -> heads ->
//                  log_prob/entropy/scatter, plus 1 pool row per block. 512 blocks x 16 cells. ----
__launch_bounds__(256)
__global__ void mega_kernel(const bf16* __restrict__ f, const float* __restrict__ instats,
                            const float* __restrict__ gamma, const float* __restrict__ beta,
                            const int* __restrict__ cell_i, const int* __restrict__ cell_j,
                            const int* __restrict__ action,
                            const bf16* __restrict__ wT, const float* __restrict__ fb1,
                            const bf16* __restrict__ wT2, const float* __restrict__ fb2,
                            const float* __restrict__ bw, const float* __restrict__ bb,
                            const float* __restrict__ iw, const float* __restrict__ ib,
                            const float* __restrict__ tw, const float* __restrict__ tb,
                            float* __restrict__ pooled, float* __restrict__ out){
  constexpr int KST = 1160;               // fc1 k stride (shorts)
  __shared__ unsigned short sG[16*KST];   // 37120 B; overlaid by h2L after FC1 reads done
  __shared__ unsigned short h1L[16*264];  // 8448 B
  __shared__ float sAB[256];
  __shared__ int sij[32];
  __shared__ float sRed[2];
  __shared__ float sP[128];
  float* h2L = (float*)sG;                // 16*132 fp32 = 8448 B (inside sG)
  const int tid = threadIdx.x;
  const int lane = tid & 63, wave = tid >> 6;
  const int quad = lane >> 4, l15 = lane & 15;
  const int cb = blockIdx.x*16;

  if (tid < 2) sRed[tid] = 0.f;
  if (tid < 128){ float A,B; computeAB(instats, gamma, beta, tid, A, B);
    sAB[tid]=A; sAB[128+tid]=B; sP[tid]=0.f; }
  if (tid < 16) sij[tid] = cell_i[cb + tid];
  else if (tid < 32) sij[tid] = cell_j[cb + tid - 16];
  __syncthreads();

  // phase 1: gather 16 cells' 3x3x128 patches (GN+ReLU) -> sG [cell][k'=rr*128+ch]
  for (int idx = tid; idx < 16*144; idx += 256){
    int c8 = idx & 15; int t2 = idx >> 4;
    int cell = t2 / 9, rr = t2 - cell*9;
    int r = rr/3, cl = rr - r*3;
    int py = sij[cell] + r, px = sij[16+cell] + cl;   // padded coords
    uint4 v = *(const uint4*)(f + ((size_t)py*PW + px)*128 + c8*8);
    bool border = (py==0) | (py==513) | (px==0) | (px==513);
    unsigned uu[4] = {v.x, v.y, v.z, v.w};
    unsigned ou[4];
    #pragma unroll
    for (int j = 0; j < 4; ++j){
      int ch = c8*8 + j*2;
      float a = border ? 0.f : fmaxf(bflo(uu[j])*sAB[ch]   + sAB[128+ch],   0.f);
      float d = border ? 0.f : fmaxf(bfhi(uu[j])*sAB[ch+1] + sAB[128+ch+1], 0.f);
      ou[j] = pack2bf(a, d);
    }
    uint4 wv; wv.x = ou[0]; wv.y = ou[1]; wv.z = ou[2]; wv.w = ou[3];
    *(uint4*)(&sG[cell*KST + rr*128 + c8*8]) = wv;
  }
  __syncthreads();

  // phase 2: FC1 MFMA (1152 -> 256), wave owns oc [wave*64, wave*64+64)
  {
    f32x4 acc[4];
    const int ocb = wave*64;
    #pragma unroll
    for (int t = 0; t < 4; ++t)
      acc[t] = *(const f32x4*)(fb1 + ocb + t*16 + quad*4);
    #pragma unroll 2
    for (int kc = 0; kc < 36; ++kc){
      short8 b = *(const short8*)(&sG[l15*KST + kc*32 + quad*8]);
      #pragma unroll
      for (int t = 0; t < 4; ++t){
        short8 a = *(const short8*)((const unsigned short*)wT + ((size_t)kc*256 + ocb + t*16 + l15)*32 + quad*8);
        acc[t] = __builtin_amdgcn_mfma_f32_16x16x32_bf16(a, b, acc[t], 0, 0, 0);
      }
    }
    // phase 3: relu -> bf16 -> h1L [cell][oc] stride 264
    #pragma unroll
    for (int t = 0; t < 4; ++t){
      f32x4 v = acc[t];
      uint2 pk;
      pk.x = pack2bf(fmaxf(v[0],0.f), fmaxf(v[1],0.f));
      pk.y = pack2bf(fmaxf(v[2],0.f), fmaxf(v[3],0.f));
      *(uint2*)(&h1L[l15*264 + ocb + t*16 + quad*4]) = pk;
    }
  }
  __syncthreads();

  // phase 4: FC2 MFMA (256 -> 128); wave owns oc [wave*32, wave*32+32)
  {
    const int och = wave*32;
    f32x4 acc2[2];
    #pragma unroll
    for (int t = 0; t < 2; ++t)
      acc2[t] = *(const f32x4*)(fb2 + och + t*16 + quad*4);
    #pragma unroll
    for (int kc = 0; kc < 8; ++kc){
      short8 b = *(const short8*)(&h1L[l15*264 + kc*32 + quad*8]);
      #pragma unroll
      for (int t = 0; t < 2; ++t){
        short8 a = *(const short8*)((const unsigned short*)wT2 + ((size_t)kc*128 + och + t*16 + l15)*32 + quad*8);
        acc2[t] = __builtin_amdgcn_mfma_f32_16x16x32_bf16(a, b, acc2[t], 0, 0, 0);
      }
    }
    // phase 5: relu -> h2L fp32 [cell][oc] stride 132 (overlays sG; sG dead since phase-3 barrier)
    #pragma unroll
    for (int t = 0; t < 2; ++t){
      f32x4 v = acc2[t];
      #pragma unroll
      for (int r = 0; r < 4; ++r) v[r] = fmaxf(v[r], 0.f);
      *(f32x4*)(&h2L[l15*132 + och + t*16 + quad*4]) = v;
    }
  }
  __syncthreads();

  // phase 6: heads (16 cells x 12 outs) + log_prob/entropy/scatter
  if (tid < 192){
    int cell = tid/12, jj = tid - cell*12;
    int which = jj >> 2, o = jj & 3;
    const float* W  = (which==0) ? bw : (which==1 ? iw : tw);
    const float* Bp = (which==0) ? bb : (which==1 ? ib : tb);
    float d = Bp[o];
    const float* h2 = &h2L[cell*132];
    for (int k = 0; k < 128; k++) d += h2[k]*W[k*4+o];
    int cellg = cb + cell;
    if (which == 1){
      out[262147 + cellg*4 + o] = d;
    } else if (which == 2){
      out[262147 + 32768 + cellg*4 + o] = d;
    } else {
      float p = 1.f/(1.f + __expf(-d));
      p = fminf(fmaxf(p, 1e-7f), 1.f - 1e-7f);
      int a = action[cellg*4 + o];
      float lp  = a ? __logf(p) : __logf(1.f-p);
      float ent = -(p*__logf(p) + (1.f-p)*__logf(1.f-p));
      atomicAdd(&sRed[0], lp);
      atomicAdd(&sRed[1], ent);
      if (a){
        const int di[4] = {-1,0,1,0};
        const int dj[4] = {0,1,0,-1};
        int ni = sij[cell] + di[o];
        int nj = sij[16+cell] + dj[o];
        if ((unsigned)ni < 512u && (unsigned)nj < 512u)
          out[ni*512 + nj] = 1.0f;
      }
    }
  }

  // phase 7: global-avg-pool, 1 row per block (512 blocks <-> 512 rows)
  {
    const int gl = tid & 15, xl = tid >> 4;
    float A[8], B[8];
    #pragma unroll
    for (int j = 0; j < 8; ++j){ A[j] = sAB[gl*8+j]; B[j] = sAB[128+gl*8+j]; }
    const int y = blockIdx.x;     // 0..511
    float ps[8] = {0,0,0,0,0,0,0,0};
    for (int x2 = xl; x2 < 512; x2 += 16){
      uint4 v = *(const uint4*)(f + ((size_t)(y+1)*PW + x2+1)*128 + gl*8);
      unsigned uu[4] = {v.x, v.y, v.z, v.w};
      #pragma unroll
      for (int j = 0; j < 4; ++j){
        ps[j*2]   += fmaxf(bflo(uu[j])*A[j*2]   + B[j*2],   0.f);
        ps[j*2+1] += fmaxf(bfhi(uu[j])*A[j*2+1] + B[j*2+1], 0.f);
      }
    }
    #pragma unroll
    for (int j = 0; j < 8; ++j) atomicAdd(&sP[gl*8+j], ps[j]);
  }
  __syncthreads();
  if (tid == 0){
    atomicAdd(&out[262144], sRed[0]);
    atomicAdd(&out[262145], sRed[1]);
  }
  if (tid < 128) atomicAdd(&pooled[tid], sP[tid]);
}

// ---------------- value head MLP ----------------
__global__ void value_kernel(const float* __restrict__ pooled, const float* __restrict__ vw1,
                             const float* __restrict__ vb1, const float* __restrict__ vw2,
                             const float* __restrict__ vb2, float* __restrict__ out){
  int t = threadIdx.x;   // 64 threads
  float h = vb1[t];
  const float invN = 1.f/262144.f;
  for (int c = 0; c < 128; c++) h += (pooled[c]*invN)*vw1[c*64+t];
  h = fmaxf(h, 0.f);
  float v = h*vw2[t];
  #pragma unroll
  for (int off = 32; off; off >>= 1) v += __shfl_xor(v, off);
  if (t == 0) out[262146] = v + vb2[0];
}

extern "C" void kernel_launch(void* const* d_in, const int* in_sizes, int n_in,
                              void* d_out, int out_size, void* d_ws, size_t ws_size,
                              hipStream_t stream) {
  (void)in_sizes; (void)n_in; (void)out_size; (void)ws_size;
  const float* x      = (const float*)d_in[0];
  const int*  cell_i  = (const int*)d_in[1];
  const int*  cell_j  = (const int*)d_in[2];
  const int*  action  = (const int*)d_in[3];
  const float* w1 = (const float*)d_in[4];  const float* b1 = (const float*)d_in[5];
  const float* g1 = (const float*)d_in[6];  const float* be1= (const float*)d_in[7];
  const float* w2 = (const float*)d_in[8];  const float* b2 = (const float*)d_in[9];
  const float* g2 = (const float*)d_in[10]; const float* be2= (const float*)d_in[11];
  const float* w3 = (const float*)d_in[12]; const float* b3 = (const float*)d_in[13];
  const float* g3 = (const float*)d_in[14]; const float* be3= (const float*)d_in[15];
  const float* fw1= (const float*)d_in[16]; const float* fb1= (const float*)d_in[17];
  const float* fw2= (const float*)d_in[18]; const float* fb2= (const float*)d_in[19];
  const float* bw = (const float*)d_in[20]; const float* bb = (const float*)d_in[21];
  const float* iw = (const float*)d_in[22]; const float* ib = (const float*)d_in[23];
  const float* tw = (const float*)d_in[24]; const float* tb = (const float*)d_in[25];
  const float* vw1= (const float*)d_in[26]; const float* vb1= (const float*)d_in[27];
  const float* vw2= (const float*)d_in[28]; const float* vb2= (const float*)d_in[29];

  float* out = (float*)d_out;
  char* ws = (char*)d_ws;
  bf16* buf1 = (bf16*)(ws);                       // 25,362,816 (+small overread slack into buf2)
  bf16* buf2 = (bf16*)(ws + 25362816);            // -> 76,088,448
  bf16* bufF = (bf16*)(ws + 76088448);            // -> 143,722,624
  bf16* wT2  = (bf16*)(ws + 143722624);           // 110,592  -> 143,833,216
  bf16* wT3  = (bf16*)(ws + 143833216);           // 221,184  -> 144,054,400
  bf16* wT1  = (bf16*)(ws + 144054400);           // 15,360   -> 144,069,760
  bf16* wF1T = (bf16*)(ws + 144069760);           // 589,824  -> 144,659,584
  bf16* wF2T = (bf16*)(ws + 144659584);           // 65,536   -> 144,725,120
  float* statsf = (float*)(ws + 144725120);       // 68 floats (L1:0, L2:12, L3:36)
  float* pooled = statsf + 128;                   // 128 floats

  setup_kernel<<<2983, 256, 0, stream>>>(out, statsf, pooled, w1, wT1, w2, wT2, w3, wT3,
                                         fw1, wF1T, fw2, wF2T);
  conv1_mfma_kernel<<<1024, 256, 0, stream>>>(x, wT1, b1, buf1, statsf + 0);
  norm_kernel<48><<<514*4, 256, 0, stream>>>(buf1, statsf + 0, g1, be1);
  // conv2: r0/r7-verified tap-major 16x16 tile, grid 32x32
  conv_dma16_kernel<48,2,3,96><<<1024, 256, 0, stream>>>(buf1, wT2, b2, buf2, statsf + 12);
  norm_kernel<96><<<514*4, 256, 0, stream>>>(buf2, statsf + 12, g2, be2);
  // conv3: r7 compute loop + tri-buffer two-phase staging (max 6 DMA at a drain), grid 32x64
  conv_dma8_kernel<96,3,2,128,4,8><<<2048, 256, 0, stream>>>(buf2, wT3, b3, bufF, statsf + 36);
  mega_kernel<<<512, 256, 0, stream>>>(bufF, statsf + 36, g3, be3, cell_i, cell_j, action,
                                       wF1T, fb1, wF2T, fb2, bw, bb, iw, ib, tw, tb,
                                       pooled, out);
  value_kernel<<<1, 64, 0, stream>>>(pooled, vw1, vb1, vw2, vb2, out);
}